// Round 1
// baseline (6197.119 us; speedup 1.0000x reference)
//
#include <hip/hip_runtime.h>

#define PP 20000
#define LL 16
#define NLK 50000
#define NNODE 4096

// workspace offsets (in floats)
#define OFF_LS0 0
#define OFF_LS1 1600000
#define OFF_NS  3200000
#define OFF_MS  3331072
#define OFF_AGG 4931072
#define OFF_CWT 5062144
#define OFF_KT  5193216
#define OFF_RKT 5199360
#define OFF_W1T 5202432
#define OFF_W2T 5214720
#define OFF_R2  5231104
#define OFF_PS  10351104
// total = 10,991,104 floats = 44.0 MB

__device__ __forceinline__ float sigm(float v) { return 1.f / (1.f + __expf(-v)); }

// ---------------- init: states + weight transposes ----------------
__global__ void k_init(const float* __restrict__ cap, const float* __restrict__ deg,
                       const float* __restrict__ traffic,
                       const float* __restrict__ gk, const float* __restrict__ grk,
                       const float* __restrict__ We1, const float* __restrict__ We2,
                       float* __restrict__ ls0, float* __restrict__ nsb, float* __restrict__ psb,
                       float* __restrict__ kT, float* __restrict__ rkT,
                       float* __restrict__ w1T, float* __restrict__ w2T)
{
  int id = blockIdx.x * 256 + threadIdx.x;
  if (id < NLK * 32) {
    int d = id & 31;
    ls0[id] = (d == 0) ? cap[id >> 5] : 0.f;
  }
  if (id < NNODE * 32) {
    int d = id & 31;
    nsb[id] = (d == 0) ? deg[id >> 5] : 0.f;
  }
  if (id < PP * 32) {
    int d = id & 31, p = id >> 5;
    psb[id] = (d == 0) ? traffic[p] : (d == 1 ? traffic[PP + p] : 0.f);
  }
  if (id < 96 * 64) { int j = id >> 6, i = id & 63; kT[id] = gk[i * 96 + j]; }
  if (id < 96 * 32) { int j = id >> 5, i = id & 31; rkT[id] = grk[i * 96 + j]; }
  if (id < 128 * 96) { int j = id / 96, i = id - j * 96; w1T[id] = We1[i * 128 + j]; }
  if (id < 128 * 128) { int j = id >> 7, i = id & 127; w2T[id] = We2[i * 128 + j]; }
}

// ---------------- fused GRU over 16 steps, 2 waves per 64-path block ----------------
__global__ __launch_bounds__(128) void k_gru(
    const float* __restrict__ ls, const float* __restrict__ nsb,
    float* __restrict__ psb, const int* __restrict__ l2p, const int* __restrict__ n2p,
    const float* __restrict__ kT, const float* __restrict__ rkT,
    const float* __restrict__ gb, float* __restrict__ ms)
{
  __shared__ float zs[64][33];
  __shared__ float rs[64][33];
  __shared__ float cxs[64][33];
  __shared__ float chs[64][33];
  const int lane = threadIdx.x & 63;
  const int role = threadIdx.x >> 6;   // wave0: j 0..47, wave1: j 48..95
  const int path = blockIdx.x * 64 + lane;
  const bool valid = path < PP;
  float h[32], x[64], xn[64];
  if (valid) {
    const float4* hp = (const float4*)(psb + (size_t)path * 32);
#pragma unroll
    for (int i = 0; i < 8; ++i) {
      float4 v = hp[i];
      h[4 * i] = v.x; h[4 * i + 1] = v.y; h[4 * i + 2] = v.z; h[4 * i + 3] = v.w;
    }
    int e = path * LL;
    const float4* lp = (const float4*)(ls + (size_t)l2p[e] * 32);
    const float4* np = (const float4*)(nsb + (size_t)n2p[e] * 32);
#pragma unroll
    for (int i = 0; i < 8; ++i) {
      float4 v = lp[i];
      x[4 * i] = v.x; x[4 * i + 1] = v.y; x[4 * i + 2] = v.z; x[4 * i + 3] = v.w;
      float4 u = np[i];
      x[32 + 4 * i] = u.x; x[32 + 4 * i + 1] = u.y; x[32 + 4 * i + 2] = u.z; x[32 + 4 * i + 3] = u.w;
    }
  }
  for (int l = 0; l < LL; ++l) {
    if (valid && l + 1 < LL) {   // prefetch next step's gather
      int e = path * LL + l + 1;
      const float4* lp = (const float4*)(ls + (size_t)l2p[e] * 32);
      const float4* np = (const float4*)(nsb + (size_t)n2p[e] * 32);
#pragma unroll
      for (int i = 0; i < 8; ++i) {
        float4 v = lp[i];
        xn[4 * i] = v.x; xn[4 * i + 1] = v.y; xn[4 * i + 2] = v.z; xn[4 * i + 3] = v.w;
        float4 u = np[i];
        xn[32 + 4 * i] = u.x; xn[32 + 4 * i + 1] = u.y; xn[32 + 4 * i + 2] = u.z; xn[32 + 4 * i + 3] = u.w;
      }
    }
    if (valid) {
      if (role == 0) {
        for (int j = 0; j < 48; ++j) {
          const float* kr = kT + j * 64;
          const float* rr = rkT + j * 32;
          float mx = gb[j], mh = gb[96 + j];
#pragma unroll
          for (int i = 0; i < 64; ++i) mx = fmaf(x[i], kr[i], mx);
#pragma unroll
          for (int i = 0; i < 32; ++i) mh = fmaf(h[i], rr[i], mh);
          float s = mx + mh;
          if (j < 32) zs[lane][j] = s; else rs[lane][j - 32] = s;
        }
      } else {
        for (int j = 48; j < 96; ++j) {
          const float* kr = kT + j * 64;
          const float* rr = rkT + j * 32;
          float mx = gb[j], mh = gb[96 + j];
#pragma unroll
          for (int i = 0; i < 64; ++i) mx = fmaf(x[i], kr[i], mx);
#pragma unroll
          for (int i = 0; i < 32; ++i) mh = fmaf(h[i], rr[i], mh);
          if (j < 64) rs[lane][j - 32] = mx + mh;
          else { cxs[lane][j - 64] = mx; chs[lane][j - 64] = mh; }  // c-gate keeps mx/mh separate
        }
      }
    }
    __syncthreads();
    if (valid) {
#pragma unroll
      for (int d = 0; d < 32; ++d) {
        float z = sigm(zs[lane][d]);
        float r = sigm(rs[lane][d]);
        float c = tanhf(cxs[lane][d] + r * chs[lane][d]);
        h[d] = z * h[d] + (1.f - z) * c;
      }
      if (role == 0) {  // outputs[p,l] -> segment_sum over links
        float* mp = ms + (size_t)l2p[path * LL + l] * 32;
#pragma unroll
        for (int d = 0; d < 32; ++d) atomicAdd(mp + d, h[d]);
      }
      if (l + 1 < LL) {
#pragma unroll
        for (int i = 0; i < 64; ++i) x[i] = xn[i];
      }
    }
    __syncthreads();
  }
  if (valid && role == 0) {
    float4* hp = (float4*)(psb + (size_t)path * 32);
#pragma unroll
    for (int i = 0; i < 8; ++i)
      hp[i] = make_float4(h[4 * i], h[4 * i + 1], h[4 * i + 2], h[4 * i + 3]);
  }
}

// ---------------- edge MLP: 2 threads per link row ----------------
__global__ __launch_bounds__(256) void k_mlp(
    const float* __restrict__ ls, float* __restrict__ lsn,
    const float* __restrict__ nsb, const float* __restrict__ ms,
    const int* __restrict__ l2n,
    const float* __restrict__ w1T, const float* __restrict__ b1,
    const float* __restrict__ w2T, const float* __restrict__ b2,
    const float* __restrict__ w3, const float* __restrict__ b3)
{
  __shared__ float buf[64][256];  // x1 staging: dynamic write, static read-back
  const int t = threadIdx.x;
  const int row = blockIdx.x * 128 + (t >> 1);
  const int hh = t & 1;
  if (row >= NLK) return;
  float con[48];
  const int nd = l2n[row];
  if (hh == 0) {  // inputs 0..47 = node[0..31], link[0..15]
    const float4* a = (const float4*)(nsb + (size_t)nd * 32);
#pragma unroll
    for (int i = 0; i < 8; ++i) { float4 v = a[i]; con[4*i]=v.x; con[4*i+1]=v.y; con[4*i+2]=v.z; con[4*i+3]=v.w; }
    const float4* b = (const float4*)(ls + (size_t)row * 32);
#pragma unroll
    for (int i = 0; i < 4; ++i) { float4 v = b[i]; con[32+4*i]=v.x; con[32+4*i+1]=v.y; con[32+4*i+2]=v.z; con[32+4*i+3]=v.w; }
  } else {        // inputs 48..95 = link[16..31], m[0..31]
    const float4* b = (const float4*)(ls + (size_t)row * 32 + 16);
#pragma unroll
    for (int i = 0; i < 4; ++i) { float4 v = b[i]; con[4*i]=v.x; con[4*i+1]=v.y; con[4*i+2]=v.z; con[4*i+3]=v.w; }
    const float4* c = (const float4*)(ms + (size_t)row * 32);
#pragma unroll
    for (int i = 0; i < 8; ++i) { float4 v = c[i]; con[16+4*i]=v.x; con[16+4*i+1]=v.y; con[16+4*i+2]=v.z; con[16+4*i+3]=v.w; }
  }
  for (int j = 0; j < 128; ++j) {
    const float* wr = w1T + j * 96 + hh * 48;
    float p = 0.f;
#pragma unroll
    for (int i = 0; i < 48; ++i) p = fmaf(con[i], wr[i], p);
    p += __shfl_xor(p, 1);
    p = fmaxf(p + b1[j], 0.f);
    if ((j >> 6) == hh) buf[j & 63][t] = p;
  }
  float x1[64];
#pragma unroll
  for (int i = 0; i < 64; ++i) x1[i] = buf[i][t];
  float acc[32];
#pragma unroll
  for (int d = 0; d < 32; ++d) acc[d] = (hh == 0) ? b3[d] : 0.f;
  for (int j = 0; j < 128; ++j) {
    const float* wr = w2T + j * 128 + hh * 64;
    float p = 0.f;
#pragma unroll
    for (int i = 0; i < 64; ++i) p = fmaf(x1[i], wr[i], p);
    p += __shfl_xor(p, 1);
    if ((j >> 6) == hh) {  // owner applies relu and streams into We3 accumulation
      float v = fmaxf(p + b2[j], 0.f);
      const float* w3r = w3 + j * 32;
#pragma unroll
      for (int d = 0; d < 32; ++d) acc[d] = fmaf(v, w3r[d], acc[d]);
    }
  }
#pragma unroll
  for (int d = 0; d < 32; ++d) acc[d] += __shfl_xor(acc[d], 1);
  if (hh == 0) {
    float4* o = (float4*)(lsn + (size_t)row * 32);
#pragma unroll
    for (int i = 0; i < 8; ++i) o[i] = make_float4(acc[4*i], acc[4*i+1], acc[4*i+2], acc[4*i+3]);
  }
}

// ---------------- link->node segment sum ----------------
__global__ void k_agg(const float* __restrict__ lsn, const int* __restrict__ l2n,
                      const int* __restrict__ n2l, float* __restrict__ agg)
{
  int id = blockIdx.x * 256 + threadIdx.x;
  if (id >= NLK * 32) return;
  int link = id >> 5, d = id & 31;
  atomicAdd(agg + (size_t)l2n[link] * 32 + d, lsn[(size_t)n2l[link] * 32 + d]);
}

// ---------------- con2 @ Wg, written transposed [32][4096] ----------------
__global__ void k_con2w(const float* __restrict__ nsb, const float* __restrict__ agg,
                        const float* __restrict__ Wg, float* __restrict__ cwT)
{
  int g = blockIdx.x * 256 + threadIdx.x;  // 32*4096
  int d = g >> 12, n = g & 4095;
  float a = 0.f;
#pragma unroll
  for (int i = 0; i < 32; ++i) a = fmaf(nsb[n * 32 + i], Wg[i * 32 + d], a);
#pragma unroll
  for (int i = 0; i < 32; ++i) a = fmaf(agg[n * 32 + i], Wg[(32 + i) * 32 + d], a);
  cwT[g] = a;
}

// ---------------- laplacian @ cw + bg -> node_state (in place) ----------------
__global__ __launch_bounds__(256) void k_lap(const float* __restrict__ lap,
    const float* __restrict__ cwT, const float* __restrict__ bg, float* __restrict__ nsb)
{
  int g = blockIdx.x * 256 + threadIdx.x;  // NNODE*32
  int d = g & 31, n = g >> 5;
  const float4* lr = (const float4*)(lap + (size_t)n * 4096);
  const float4* cr = (const float4*)(cwT + (size_t)d * 4096);
  float a = 0.f;
#pragma unroll 4
  for (int k = 0; k < 1024; ++k) {
    float4 av = lr[k], bv = cr[k];
    a += av.x * bv.x + av.y * bv.y + av.z * bv.z + av.w * bv.w;
  }
  nsb[g] = a + bg[d];
}

// ---------------- readout ----------------
__global__ void k_r1(const float* __restrict__ psb, const float* __restrict__ Wr1,
                     const float* __restrict__ br1, float* __restrict__ r1)
{
  int g = blockIdx.x * 256 + threadIdx.x; // PP*256
  int j = g & 255, p = g >> 8;
  float a = br1[j];
#pragma unroll
  for (int i = 0; i < 32; ++i) a = fmaf(psb[(size_t)p * 32 + i], Wr1[i * 256 + j], a);
  r1[g] = fmaxf(a, 0.f);
}

__global__ void k_r2(const float* __restrict__ r1, const float* __restrict__ Wr2,
                     const float* __restrict__ br2, float* __restrict__ r2)
{
  int g = blockIdx.x * 256 + threadIdx.x; // PP*64
  int p = g >> 6, jt = (g & 63) << 2;
  float a0 = br2[jt], a1 = br2[jt + 1], a2 = br2[jt + 2], a3 = br2[jt + 3];
  const float4* rr = (const float4*)(r1 + (size_t)p * 256);
#pragma unroll 4
  for (int i4 = 0; i4 < 64; ++i4) {
    float4 r = rr[i4];
    const float* wb = Wr2 + (i4 * 4) * 256 + jt;
    float4 w0 = *(const float4*)(wb);
    float4 w1 = *(const float4*)(wb + 256);
    float4 w2 = *(const float4*)(wb + 512);
    float4 w3v = *(const float4*)(wb + 768);
    a0 += r.x * w0.x + r.y * w1.x + r.z * w2.x + r.w * w3v.x;
    a1 += r.x * w0.y + r.y * w1.y + r.z * w2.y + r.w * w3v.y;
    a2 += r.x * w0.z + r.y * w1.z + r.z * w2.z + r.w * w3v.z;
    a3 += r.x * w0.w + r.y * w1.w + r.z * w2.w + r.w * w3v.w;
  }
  *(float4*)(r2 + (size_t)p * 256 + jt) =
      make_float4(fmaxf(a0, 0.f), fmaxf(a1, 0.f), fmaxf(a2, 0.f), fmaxf(a3, 0.f));
}

__global__ void k_out(const float* __restrict__ r2, const float* __restrict__ psb,
                      const float* __restrict__ Wf, const float* __restrict__ bf,
                      float* __restrict__ out)
{
  int p = blockIdx.x * 256 + threadIdx.x;
  if (p >= PP) return;
  float a = bf[0];
  const float4* rr = (const float4*)(r2 + (size_t)p * 256);
  const float4* wf = (const float4*)Wf;
#pragma unroll 8
  for (int i = 0; i < 64; ++i) {
    float4 v = rr[i], w = wf[i];
    a += v.x * w.x + v.y * w.y + v.z * w.z + v.w * w.w;
  }
  const float4* pr = (const float4*)(psb + (size_t)p * 32);
#pragma unroll
  for (int i = 0; i < 8; ++i) {
    float4 v = pr[i], w = wf[64 + i];
    a += v.x * w.x + v.y * w.y + v.z * w.z + v.w * w.w;
  }
  out[p] = a;
}

extern "C" void kernel_launch(void* const* d_in, const int* in_sizes, int n_in,
                              void* d_out, int out_size, void* d_ws, size_t ws_size,
                              hipStream_t stream) {
  const float* capacities = (const float*)d_in[0];
  const float* degrees    = (const float*)d_in[1];
  const float* traffic    = (const float*)d_in[2];
  const float* lap        = (const float*)d_in[3];
  const int*   l2p        = (const int*)d_in[6];   // links_to_paths
  const int*   n2p        = (const int*)d_in[7];   // nodes_to_paths
  const int*   l2n        = (const int*)d_in[8];   // links_to_nodes
  const int*   n2l        = (const int*)d_in[9];   // nodes_to_links
  const float* gk  = (const float*)d_in[13];
  const float* grk = (const float*)d_in[14];
  const float* gb  = (const float*)d_in[15];
  const float* We1 = (const float*)d_in[16]; const float* be1 = (const float*)d_in[17];
  const float* We2 = (const float*)d_in[18]; const float* be2 = (const float*)d_in[19];
  const float* We3 = (const float*)d_in[20]; const float* be3 = (const float*)d_in[21];
  const float* Wg  = (const float*)d_in[22]; const float* bg  = (const float*)d_in[23];
  const float* Wr1 = (const float*)d_in[24]; const float* br1 = (const float*)d_in[25];
  const float* Wr2 = (const float*)d_in[26]; const float* br2 = (const float*)d_in[27];
  const float* Wf  = (const float*)d_in[28]; const float* bf  = (const float*)d_in[29];

  float* w   = (float*)d_ws;
  float* ls0 = w + OFF_LS0;
  float* ls1 = w + OFF_LS1;
  float* nsb = w + OFF_NS;
  float* ms  = w + OFF_MS;
  float* agg = w + OFF_AGG;
  float* cwT = w + OFF_CWT;
  float* kT  = w + OFF_KT;
  float* rkT = w + OFF_RKT;
  float* w1T = w + OFF_W1T;
  float* w2T = w + OFF_W2T;
  float* r1  = w + OFF_LS0;   // readout-phase alias over dead iteration buffers
  float* r2  = w + OFF_R2;
  float* psb = w + OFF_PS;

  k_init<<<6250, 256, 0, stream>>>(capacities, degrees, traffic, gk, grk, We1, We2,
                                   ls0, nsb, psb, kT, rkT, w1T, w2T);
  for (int t = 0; t < 4; ++t) {
    float* lsi = (t & 1) ? ls1 : ls0;
    float* lso = (t & 1) ? ls0 : ls1;
    hipMemsetAsync(ms, 0, (size_t)NLK * 32 * sizeof(float), stream);
    hipMemsetAsync(agg, 0, (size_t)NNODE * 32 * sizeof(float), stream);
    k_gru<<<313, 128, 0, stream>>>(lsi, nsb, psb, l2p, n2p, kT, rkT, gb, ms);
    k_mlp<<<391, 256, 0, stream>>>(lsi, lso, nsb, ms, l2n, w1T, be1, w2T, be2, We3, be3);
    k_agg<<<6250, 256, 0, stream>>>(lso, l2n, n2l, agg);
    k_con2w<<<512, 256, 0, stream>>>(nsb, agg, Wg, cwT);
    k_lap<<<512, 256, 0, stream>>>(lap, cwT, bg, nsb);
  }
  k_r1<<<20000, 256, 0, stream>>>(psb, Wr1, br1, r1);
  k_r2<<<5000, 256, 0, stream>>>(r1, Wr2, br2, r2);
  k_out<<<79, 256, 0, stream>>>(r2, psb, Wf, bf, (float*)d_out);
}

// Round 3
// 2034.392 us; speedup vs baseline: 3.0462x; 3.0462x over previous
//
#include <hip/hip_runtime.h>

#define PP 20000
#define LL 16
#define NLK 50000
#define NNODE 4096

// workspace offsets (in floats)
#define OFF_LS0 0
#define OFF_LS1 1600000
#define OFF_NS  3200000
#define OFF_MS  3331072
#define OFF_AGG 4931072
#define OFF_CWT 5062144
#define OFF_WF  5193216   // frag-ordered bf16 MLP weights hi+lo (65536 ushorts = 32768 floats)
#define OFF_R2  5231104
#define OFF_PS  10351104
// total = 10,991,104 floats = 44.0 MB

typedef __attribute__((ext_vector_type(8))) short s16x8;
typedef __attribute__((ext_vector_type(4))) float f32x4;

__device__ __forceinline__ float sigm(float v) { return 1.f / (1.f + __expf(-v)); }
__device__ __forceinline__ float tanhf_fast(float x) {
  float e = __expf(-2.f * x);
  return 2.f / (1.f + e) - 1.f;
}
__device__ __forceinline__ unsigned short f2bf(float f) {
  unsigned int u = __float_as_uint(f);
  return (unsigned short)((u + 0x7FFFu + ((u >> 16) & 1u)) >> 16);
}
__device__ __forceinline__ float bf2f(unsigned short u) {
  return __uint_as_float(((unsigned int)u) << 16);
}
// split f into hi (bf16 RTN) + lo (bf16 of residual): together ~fp32-accurate
__device__ __forceinline__ void splitf(float f, unsigned short& h, unsigned short& l) {
  unsigned short hh = f2bf(f);
  h = hh;
  l = f2bf(f - bf2f(hh));
}
__device__ __forceinline__ void pack8s(float4 a, float4 b, s16x8& vh, s16x8& vl) {
  float t[8] = {a.x, a.y, a.z, a.w, b.x, b.y, b.z, b.w};
#pragma unroll
  for (int i = 0; i < 8; ++i) {
    unsigned short h_, l_;
    splitf(t[i], h_, l_);
    vh[i] = (short)h_; vl[i] = (short)l_;
  }
}

#define MM(ACC, A, B) ACC = __builtin_amdgcn_mfma_f32_16x16x32_bf16(A, B, ACC, 0, 0, 0)
// full split product: hi*hi + lo*hi + hi*lo
#define MM3(ACC, AH, AL, BH, BL) do { MM(ACC, AH, BH); MM(ACC, AL, BH); MM(ACC, AH, BL); } while (0)

// ---------------- init: states ----------------
__global__ void k_init(const float* __restrict__ cap, const float* __restrict__ deg,
                       const float* __restrict__ traffic,
                       float* __restrict__ ls0, float* __restrict__ nsb, float* __restrict__ psb)
{
  int id = blockIdx.x * 256 + threadIdx.x;
  if (id < NLK * 32) {
    int d = id & 31;
    ls0[id] = (d == 0) ? cap[id >> 5] : 0.f;
  }
  if (id < NNODE * 32) {
    int d = id & 31;
    nsb[id] = (d == 0) ? deg[id >> 5] : 0.f;
  }
  if (id < PP * 32) {
    int d = id & 31, p = id >> 5;
    psb[id] = (d == 0) ? traffic[p] : (d == 1 ? traffic[PP + p] : 0.f);
  }
}

// ---------------- prep: frag-ordered bf16 MLP weights, hi at fid, lo at fid+64 ----------------
// frag f holds, for lane L (lo=L&15, hi=L>>4), elems e: W[k = ks*32+hi*8+e][j = nt*16+lo]
// wf1: fid = nt*3+ks (24 frags), wf2: 24 + nt*4+ks (32), wf3: 56 + nt*4+ks (8)
__global__ void k_prep(const float* __restrict__ We1, const float* __restrict__ We2,
                       const float* __restrict__ We3, unsigned short* __restrict__ wf)
{
  int t = blockIdx.x * 256 + threadIdx.x;
  if (t >= 64 * 64) return;
  int fid = t >> 6, lane = t & 63;
  int lo = lane & 15, hi = lane >> 4;
  s16x8 vh, vl;
#pragma unroll
  for (int e = 0; e < 8; ++e) {
    float wv;
    if (fid < 24) {
      int nt = fid / 3, ks = fid % 3;
      wv = We1[(ks * 32 + hi * 8 + e) * 128 + nt * 16 + lo];
    } else if (fid < 56) {
      int f = fid - 24, nt = f >> 2, ks = f & 3;
      wv = We2[(ks * 32 + hi * 8 + e) * 128 + nt * 16 + lo];
    } else {
      int f = fid - 56, nt = f >> 2, ks = f & 3;
      wv = We3[(ks * 32 + hi * 8 + e) * 32 + nt * 16 + lo];
    }
    unsigned short h_, l_;
    splitf(wv, h_, l_);
    vh[e] = (short)h_; vl[e] = (short)l_;
  }
  *(s16x8*)(wf + (size_t)fid * 512 + lane * 8) = vh;
  *(s16x8*)(wf + (size_t)(fid + 64) * 512 + lane * 8) = vl;
}

// ---------------- GRU via MFMA (split precision): 16 paths/block, 2 waves split gate cols ----------------
__global__ __launch_bounds__(128) void k_gru_mfma(
    const float* __restrict__ ls, const float* __restrict__ nsb, float* __restrict__ psb,
    const int* __restrict__ l2p, const int* __restrict__ n2p,
    const float* __restrict__ gk, const float* __restrict__ grk,
    const float* __restrict__ gb, float* __restrict__ ms)
{
  __shared__ __align__(16) unsigned short hbh[2][16][40];
  __shared__ __align__(16) unsigned short hbl[2][16][40];
  const int lane = threadIdx.x & 63;
  const int w = threadIdx.x >> 6;          // wave 0: d 0..15, wave 1: d 16..31
  const int lo = lane & 15, hi = lane >> 4;
  const int pb = blockIdx.x * 16;
  const int d = w * 16 + lo;               // output col within each gate

  // weight B-frags, hi+lo (k = kbase + hi*8 + e, col j)
  s16x8 wz0h, wz0l, wz1h, wz1l, whzh, whzl;
  s16x8 wr0h, wr0l, wr1h, wr1l, whrh, whrl;
  s16x8 wc0h, wc0l, wc1h, wc1l, whch, whcl;
#pragma unroll
  for (int e = 0; e < 8; ++e) {
    int k0 = hi * 8 + e, k1 = 32 + hi * 8 + e;
    unsigned short h_, l_;
    splitf(gk[k0 * 96 + d], h_, l_);       wz0h[e] = (short)h_; wz0l[e] = (short)l_;
    splitf(gk[k1 * 96 + d], h_, l_);       wz1h[e] = (short)h_; wz1l[e] = (short)l_;
    splitf(gk[k0 * 96 + 32 + d], h_, l_);  wr0h[e] = (short)h_; wr0l[e] = (short)l_;
    splitf(gk[k1 * 96 + 32 + d], h_, l_);  wr1h[e] = (short)h_; wr1l[e] = (short)l_;
    splitf(gk[k0 * 96 + 64 + d], h_, l_);  wc0h[e] = (short)h_; wc0l[e] = (short)l_;
    splitf(gk[k1 * 96 + 64 + d], h_, l_);  wc1h[e] = (short)h_; wc1l[e] = (short)l_;
    splitf(grk[k0 * 96 + d], h_, l_);      whzh[e] = (short)h_; whzl[e] = (short)l_;
    splitf(grk[k0 * 96 + 32 + d], h_, l_); whrh[e] = (short)h_; whrl[e] = (short)l_;
    splitf(grk[k0 * 96 + 64 + d], h_, l_); whch[e] = (short)h_; whcl[e] = (short)l_;
  }
  const float bzb = gb[d] + gb[96 + d];
  const float brb = gb[32 + d] + gb[96 + 32 + d];
  const float bcx = gb[64 + d];
  const float bch = gb[96 + 64 + d];

  // h0 in C layout: lane holds rows hi*4+q, col d
  float h[4];
#pragma unroll
  for (int q = 0; q < 4; ++q) {
    h[q] = psb[(size_t)(pb + hi * 4 + q) * 32 + d];
    unsigned short h_, l_;
    splitf(h[q], h_, l_);
    hbh[0][hi * 4 + q][d] = h_;
    hbl[0][hi * 4 + q][d] = l_;
  }
  __syncthreads();
  s16x8 ahh = *(const s16x8*)&hbh[0][lo][hi * 8];
  s16x8 ahl = *(const s16x8*)&hbl[0][lo][hi * 8];

  // x frags for step 0 (A row = lo, k-chunk = hi*8)
  s16x8 ax0h, ax0l, ax1h, ax1l;
  {
    int eA = (pb + lo) * 16;
    const float4* lp = (const float4*)(ls + (size_t)l2p[eA] * 32 + hi * 8);
    const float4* np = (const float4*)(nsb + (size_t)n2p[eA] * 32 + hi * 8);
    pack8s(lp[0], lp[1], ax0h, ax0l);
    pack8s(np[0], np[1], ax1h, ax1l);
  }

  for (int l = 0; l < LL; ++l) {
    s16x8 nx0h, nx0l, nx1h, nx1l;
    if (l + 1 < LL) {  // prefetch next step's gather
      int e2 = (pb + lo) * 16 + l + 1;
      const float4* lp = (const float4*)(ls + (size_t)l2p[e2] * 32 + hi * 8);
      const float4* np = (const float4*)(nsb + (size_t)n2p[e2] * 32 + hi * 8);
      pack8s(lp[0], lp[1], nx0h, nx0l);
      pack8s(np[0], np[1], nx1h, nx1l);
    }
    f32x4 az = {bzb, bzb, bzb, bzb};
    f32x4 ar = {brb, brb, brb, brb};
    f32x4 acx = {bcx, bcx, bcx, bcx};
    f32x4 ach = {bch, bch, bch, bch};
    MM3(az, ax0h, ax0l, wz0h, wz0l);
    MM3(az, ax1h, ax1l, wz1h, wz1l);
    MM3(az, ahh, ahl, whzh, whzl);
    MM3(ar, ax0h, ax0l, wr0h, wr0l);
    MM3(ar, ax1h, ax1l, wr1h, wr1l);
    MM3(ar, ahh, ahl, whrh, whrl);
    MM3(acx, ax0h, ax0l, wc0h, wc0l);
    MM3(acx, ax1h, ax1l, wc1h, wc1l);
    MM3(ach, ahh, ahl, whch, whcl);

    const int ebase = (pb + hi * 4) * 16 + l;
#pragma unroll
    for (int q = 0; q < 4; ++q) {
      float z = sigm(az[q]);
      float r = sigm(ar[q]);
      float c = tanhf_fast(acx[q] + r * ach[q]);
      h[q] = z * h[q] + (1.f - z) * c;
      int link = l2p[ebase + q * 16];
      atomicAdd(ms + (size_t)link * 32 + d, h[q]);
    }
    if (l + 1 < LL) {
      int b = (l + 1) & 1;
#pragma unroll
      for (int q = 0; q < 4; ++q) {
        unsigned short h_, l_;
        splitf(h[q], h_, l_);
        hbh[b][hi * 4 + q][d] = h_;
        hbl[b][hi * 4 + q][d] = l_;
      }
      __syncthreads();
      ahh = *(const s16x8*)&hbh[b][lo][hi * 8];
      ahl = *(const s16x8*)&hbl[b][lo][hi * 8];
      ax0h = nx0h; ax0l = nx0l; ax1h = nx1h; ax1l = nx1l;
    }
  }
#pragma unroll
  for (int q = 0; q < 4; ++q)
    psb[(size_t)(pb + hi * 4 + q) * 32 + d] = h[q];
}

// ---------------- edge MLP via MFMA (split precision): 16 rows per 1-wave block ----------------
__global__ __launch_bounds__(64) void k_mlp_mfma(
    const float* __restrict__ lsi, float* __restrict__ lso,
    const float* __restrict__ nsb, const float* __restrict__ ms,
    const int* __restrict__ l2n, const unsigned short* __restrict__ wf,
    const float* __restrict__ be1, const float* __restrict__ be2, const float* __restrict__ be3)
{
  __shared__ __align__(16) unsigned short abh[4][64][8];
  __shared__ __align__(16) unsigned short abl[4][64][8];
  const int lane = threadIdx.x;
  const int lo = lane & 15, hi = lane >> 4;
  const int row = blockIdx.x * 16 + lo;

  // layer-1 A frags: con = [node(32) | link(32) | m(32)]
  const int nd = l2n[row];
  const float4* a0p = (const float4*)(nsb + (size_t)nd * 32 + hi * 8);
  const float4* a1p = (const float4*)(lsi + (size_t)row * 32 + hi * 8);
  const float4* a2p = (const float4*)(ms + (size_t)row * 32 + hi * 8);
  s16x8 f0h, f0l, f1h, f1l, f2h, f2l;
  pack8s(a0p[0], a0p[1], f0h, f0l);
  pack8s(a1p[0], a1p[1], f1h, f1l);
  pack8s(a2p[0], a2p[1], f2h, f2l);

#define WH(F) (*(const s16x8*)(wf + (size_t)(F) * 512 + lane * 8))
#define WL(F) (*(const s16x8*)(wf + (size_t)((F) + 64) * 512 + lane * 8))

  // layer 1 -> abuf (A-frag order for layer 2)
#pragma unroll
  for (int nt = 0; nt < 8; ++nt) {
    float bias = be1[nt * 16 + lo];
    f32x4 acc = {bias, bias, bias, bias};
    MM3(acc, f0h, f0l, WH(nt * 3 + 0), WL(nt * 3 + 0));
    MM3(acc, f1h, f1l, WH(nt * 3 + 1), WL(nt * 3 + 1));
    MM3(acc, f2h, f2l, WH(nt * 3 + 2), WL(nt * 3 + 2));
#pragma unroll
    for (int q = 0; q < 4; ++q) {
      float v = fmaxf(acc[q], 0.f);
      int rrow = hi * 4 + q, col = nt * 16 + lo;
      unsigned short h_, l_;
      splitf(v, h_, l_);
      abh[col >> 5][rrow + 16 * ((col >> 3) & 3)][col & 7] = h_;
      abl[col >> 5][rrow + 16 * ((col >> 3) & 3)][col & 7] = l_;
    }
  }
  __syncthreads();
  s16x8 x0h = *(const s16x8*)&abh[0][lane][0];
  s16x8 x1h = *(const s16x8*)&abh[1][lane][0];
  s16x8 x2h = *(const s16x8*)&abh[2][lane][0];
  s16x8 x3h = *(const s16x8*)&abh[3][lane][0];
  s16x8 x0l = *(const s16x8*)&abl[0][lane][0];
  s16x8 x1l = *(const s16x8*)&abl[1][lane][0];
  s16x8 x2l = *(const s16x8*)&abl[2][lane][0];
  s16x8 x3l = *(const s16x8*)&abl[3][lane][0];
  __syncthreads();

  // layer 2 -> abuf
#pragma unroll
  for (int nt = 0; nt < 8; ++nt) {
    float bias = be2[nt * 16 + lo];
    f32x4 acc = {bias, bias, bias, bias};
    MM3(acc, x0h, x0l, WH(24 + nt * 4 + 0), WL(24 + nt * 4 + 0));
    MM3(acc, x1h, x1l, WH(24 + nt * 4 + 1), WL(24 + nt * 4 + 1));
    MM3(acc, x2h, x2l, WH(24 + nt * 4 + 2), WL(24 + nt * 4 + 2));
    MM3(acc, x3h, x3l, WH(24 + nt * 4 + 3), WL(24 + nt * 4 + 3));
#pragma unroll
    for (int q = 0; q < 4; ++q) {
      float v = fmaxf(acc[q], 0.f);
      int rrow = hi * 4 + q, col = nt * 16 + lo;
      unsigned short h_, l_;
      splitf(v, h_, l_);
      abh[col >> 5][rrow + 16 * ((col >> 3) & 3)][col & 7] = h_;
      abl[col >> 5][rrow + 16 * ((col >> 3) & 3)][col & 7] = l_;
    }
  }
  __syncthreads();
  x0h = *(const s16x8*)&abh[0][lane][0];
  x1h = *(const s16x8*)&abh[1][lane][0];
  x2h = *(const s16x8*)&abh[2][lane][0];
  x3h = *(const s16x8*)&abh[3][lane][0];
  x0l = *(const s16x8*)&abl[0][lane][0];
  x1l = *(const s16x8*)&abl[1][lane][0];
  x2l = *(const s16x8*)&abl[2][lane][0];
  x3l = *(const s16x8*)&abl[3][lane][0];

  // layer 3 (no relu)
#pragma unroll
  for (int nt = 0; nt < 2; ++nt) {
    float bias = be3[nt * 16 + lo];
    f32x4 acc = {bias, bias, bias, bias};
    MM3(acc, x0h, x0l, WH(56 + nt * 4 + 0), WL(56 + nt * 4 + 0));
    MM3(acc, x1h, x1l, WH(56 + nt * 4 + 1), WL(56 + nt * 4 + 1));
    MM3(acc, x2h, x2l, WH(56 + nt * 4 + 2), WL(56 + nt * 4 + 2));
    MM3(acc, x3h, x3l, WH(56 + nt * 4 + 3), WL(56 + nt * 4 + 3));
#pragma unroll
    for (int q = 0; q < 4; ++q)
      lso[(size_t)(blockIdx.x * 16 + hi * 4 + q) * 32 + nt * 16 + lo] = acc[q];
  }
#undef WH
#undef WL
}

// ---------------- link->node segment sum ----------------
__global__ void k_agg(const float* __restrict__ lsn, const int* __restrict__ l2n,
                      const int* __restrict__ n2l, float* __restrict__ agg)
{
  int id = blockIdx.x * 256 + threadIdx.x;
  if (id >= NLK * 32) return;
  int link = id >> 5, d = id & 31;
  atomicAdd(agg + (size_t)l2n[link] * 32 + d, lsn[(size_t)n2l[link] * 32 + d]);
}

// ---------------- con2 @ Wg, written transposed [32][4096] ----------------
__global__ void k_con2w(const float* __restrict__ nsb, const float* __restrict__ agg,
                        const float* __restrict__ Wg, float* __restrict__ cwT)
{
  int g = blockIdx.x * 256 + threadIdx.x;  // 32*4096
  int d = g >> 12, n = g & 4095;
  float a = 0.f;
#pragma unroll
  for (int i = 0; i < 32; ++i) a = fmaf(nsb[n * 32 + i], Wg[i * 32 + d], a);
#pragma unroll
  for (int i = 0; i < 32; ++i) a = fmaf(agg[n * 32 + i], Wg[(32 + i) * 32 + d], a);
  cwT[g] = a;
}

// ---------------- laplacian @ cw + bg -> node_state ----------------
__global__ __launch_bounds__(256) void k_lap(const float* __restrict__ lap,
    const float* __restrict__ cwT, const float* __restrict__ bg, float* __restrict__ nsb)
{
  int g = blockIdx.x * 256 + threadIdx.x;  // NNODE*32
  int d = g & 31, n = g >> 5;
  const float4* lr = (const float4*)(lap + (size_t)n * 4096);
  const float4* cr = (const float4*)(cwT + (size_t)d * 4096);
  float a = 0.f;
#pragma unroll 4
  for (int k = 0; k < 1024; ++k) {
    float4 av = lr[k], bv = cr[k];
    a += av.x * bv.x + av.y * bv.y + av.z * bv.z + av.w * bv.w;
  }
  nsb[g] = a + bg[d];
}

// ---------------- readout ----------------
__global__ void k_r1(const float* __restrict__ psb, const float* __restrict__ Wr1,
                     const float* __restrict__ br1, float* __restrict__ r1)
{
  int g = blockIdx.x * 256 + threadIdx.x; // PP*256
  int j = g & 255, p = g >> 8;
  float a = br1[j];
#pragma unroll
  for (int i = 0; i < 32; ++i) a = fmaf(psb[(size_t)p * 32 + i], Wr1[i * 256 + j], a);
  r1[g] = fmaxf(a, 0.f);
}

__global__ void k_r2(const float* __restrict__ r1, const float* __restrict__ Wr2,
                     const float* __restrict__ br2, float* __restrict__ r2)
{
  int g = blockIdx.x * 256 + threadIdx.x; // PP*64
  int p = g >> 6, jt = (g & 63) << 2;
  float a0 = br2[jt], a1 = br2[jt + 1], a2 = br2[jt + 2], a3 = br2[jt + 3];
  const float4* rr = (const float4*)(r1 + (size_t)p * 256);
#pragma unroll 4
  for (int i4 = 0; i4 < 64; ++i4) {
    float4 r = rr[i4];
    const float* wb = Wr2 + (i4 * 4) * 256 + jt;
    float4 w0 = *(const float4*)(wb);
    float4 w1 = *(const float4*)(wb + 256);
    float4 w2 = *(const float4*)(wb + 512);
    float4 w3v = *(const float4*)(wb + 768);
    a0 += r.x * w0.x + r.y * w1.x + r.z * w2.x + r.w * w3v.x;
    a1 += r.x * w0.y + r.y * w1.y + r.z * w2.y + r.w * w3v.y;
    a2 += r.x * w0.z + r.y * w1.z + r.z * w2.z + r.w * w3v.z;
    a3 += r.x * w0.w + r.y * w1.w + r.z * w2.w + r.w * w3v.w;
  }
  *(float4*)(r2 + (size_t)p * 256 + jt) =
      make_float4(fmaxf(a0, 0.f), fmaxf(a1, 0.f), fmaxf(a2, 0.f), fmaxf(a3, 0.f));
}

__global__ void k_out(const float* __restrict__ r2, const float* __restrict__ psb,
                      const float* __restrict__ Wf, const float* __restrict__ bf,
                      float* __restrict__ out)
{
  int p = blockIdx.x * 256 + threadIdx.x;
  if (p >= PP) return;
  float a = bf[0];
  const float4* rr = (const float4*)(r2 + (size_t)p * 256);
  const float4* wf = (const float4*)Wf;
#pragma unroll 8
  for (int i = 0; i < 64; ++i) {
    float4 v = rr[i], w = wf[i];
    a += v.x * w.x + v.y * w.y + v.z * w.z + v.w * w.w;
  }
  const float4* pr = (const float4*)(psb + (size_t)p * 32);
#pragma unroll
  for (int i = 0; i < 8; ++i) {
    float4 v = pr[i], w = wf[64 + i];
    a += v.x * w.x + v.y * w.y + v.z * w.z + v.w * w.w;
  }
  out[p] = a;
}

extern "C" void kernel_launch(void* const* d_in, const int* in_sizes, int n_in,
                              void* d_out, int out_size, void* d_ws, size_t ws_size,
                              hipStream_t stream) {
  const float* capacities = (const float*)d_in[0];
  const float* degrees    = (const float*)d_in[1];
  const float* traffic    = (const float*)d_in[2];
  const float* lap        = (const float*)d_in[3];
  const int*   l2p        = (const int*)d_in[6];
  const int*   n2p        = (const int*)d_in[7];
  const int*   l2n        = (const int*)d_in[8];
  const int*   n2l        = (const int*)d_in[9];
  const float* gk  = (const float*)d_in[13];
  const float* grk = (const float*)d_in[14];
  const float* gb  = (const float*)d_in[15];
  const float* We1 = (const float*)d_in[16]; const float* be1 = (const float*)d_in[17];
  const float* We2 = (const float*)d_in[18]; const float* be2 = (const float*)d_in[19];
  const float* We3 = (const float*)d_in[20]; const float* be3 = (const float*)d_in[21];
  const float* Wg  = (const float*)d_in[22]; const float* bg  = (const float*)d_in[23];
  const float* Wr1 = (const float*)d_in[24]; const float* br1 = (const float*)d_in[25];
  const float* Wr2 = (const float*)d_in[26]; const float* br2 = (const float*)d_in[27];
  const float* Wf  = (const float*)d_in[28]; const float* bf  = (const float*)d_in[29];

  float* w   = (float*)d_ws;
  float* ls0 = w + OFF_LS0;
  float* ls1 = w + OFF_LS1;
  float* nsb = w + OFF_NS;
  float* ms  = w + OFF_MS;
  float* agg = w + OFF_AGG;
  float* cwT = w + OFF_CWT;
  unsigned short* wfb = (unsigned short*)(w + OFF_WF);
  float* r1  = w + OFF_LS0;   // readout-phase alias over dead iteration buffers
  float* r2  = w + OFF_R2;
  float* psb = w + OFF_PS;

  k_init<<<6250, 256, 0, stream>>>(capacities, degrees, traffic, ls0, nsb, psb);
  k_prep<<<16, 256, 0, stream>>>(We1, We2, We3, wfb);
  for (int t = 0; t < 4; ++t) {
    float* lsi = (t & 1) ? ls1 : ls0;
    float* lso = (t & 1) ? ls0 : ls1;
    hipMemsetAsync(ms, 0, (size_t)NLK * 32 * sizeof(float), stream);
    hipMemsetAsync(agg, 0, (size_t)NNODE * 32 * sizeof(float), stream);
    k_gru_mfma<<<1250, 128, 0, stream>>>(lsi, nsb, psb, l2p, n2p, gk, grk, gb, ms);
    k_mlp_mfma<<<3125, 64, 0, stream>>>(lsi, lso, nsb, ms, l2n, wfb, be1, be2, be3);
    k_agg<<<6250, 256, 0, stream>>>(lso, l2n, n2l, agg);
    k_con2w<<<512, 256, 0, stream>>>(nsb, agg, Wg, cwT);
    k_lap<<<512, 256, 0, stream>>>(lap, cwT, bg, nsb);
  }
  k_r1<<<20000, 256, 0, stream>>>(psb, Wr1, br1, r1);
  k_r2<<<5000, 256, 0, stream>>>(r1, Wr2, br2, r2);
  k_out<<<79, 256, 0, stream>>>(r2, psb, Wf, bf, (float*)d_out);
}

// Round 4
// 1025.476 us; speedup vs baseline: 6.0432x; 1.9839x over previous
//
#include <hip/hip_runtime.h>

#define PP 20000
#define LL 16
#define NLK 50000
#define NNODE 4096

// workspace offsets (in floats)
#define OFF_LS0 0
#define OFF_LS1 1600000
#define OFF_NS  3200000
#define OFF_MS  3331072
#define OFF_AGG 4931072
#define OFF_CWB 5062144   // cw split-bf16: hi [32][4096] ushort, then lo [32][4096] ushort (=131072 floats)
#define OFF_WF  5193216   // frag-ordered bf16 MLP weights hi+lo (65536 ushorts = 32768 floats)
#define OFF_R2  5231104
#define OFF_PS  10351104
// total = 10,991,104 floats = 44.0 MB

typedef __attribute__((ext_vector_type(8))) short s16x8;
typedef __attribute__((ext_vector_type(4))) float f32x4;

__device__ __forceinline__ float sigm(float v) { return 1.f / (1.f + __expf(-v)); }
__device__ __forceinline__ float tanhf_fast(float x) {
  float e = __expf(-2.f * x);
  return 2.f / (1.f + e) - 1.f;
}
__device__ __forceinline__ unsigned short f2bf(float f) {
  unsigned int u = __float_as_uint(f);
  return (unsigned short)((u + 0x7FFFu + ((u >> 16) & 1u)) >> 16);
}
__device__ __forceinline__ float bf2f(unsigned short u) {
  return __uint_as_float(((unsigned int)u) << 16);
}
// split f into hi (bf16 RTN) + lo (bf16 of residual): together ~fp32-accurate
__device__ __forceinline__ void splitf(float f, unsigned short& h, unsigned short& l) {
  unsigned short hh = f2bf(f);
  h = hh;
  l = f2bf(f - bf2f(hh));
}
__device__ __forceinline__ void pack8s(float4 a, float4 b, s16x8& vh, s16x8& vl) {
  float t[8] = {a.x, a.y, a.z, a.w, b.x, b.y, b.z, b.w};
#pragma unroll
  for (int i = 0; i < 8; ++i) {
    unsigned short h_, l_;
    splitf(t[i], h_, l_);
    vh[i] = (short)h_; vl[i] = (short)l_;
  }
}

#define MM(ACC, A, B) ACC = __builtin_amdgcn_mfma_f32_16x16x32_bf16(A, B, ACC, 0, 0, 0)
// full split product: hi*hi + lo*hi + hi*lo
#define MM3(ACC, AH, AL, BH, BL) do { MM(ACC, AH, BH); MM(ACC, AL, BH); MM(ACC, AH, BL); } while (0)

// ---------------- init: states ----------------
__global__ void k_init(const float* __restrict__ cap, const float* __restrict__ deg,
                       const float* __restrict__ traffic,
                       float* __restrict__ ls0, float* __restrict__ nsb, float* __restrict__ psb)
{
  int id = blockIdx.x * 256 + threadIdx.x;
  if (id < NLK * 32) {
    int d = id & 31;
    ls0[id] = (d == 0) ? cap[id >> 5] : 0.f;
  }
  if (id < NNODE * 32) {
    int d = id & 31;
    nsb[id] = (d == 0) ? deg[id >> 5] : 0.f;
  }
  if (id < PP * 32) {
    int d = id & 31, p = id >> 5;
    psb[id] = (d == 0) ? traffic[p] : (d == 1 ? traffic[PP + p] : 0.f);
  }
}

// ---------------- prep: frag-ordered bf16 MLP weights, hi at fid, lo at fid+64 ----------------
// frag f holds, for lane L (lo=L&15, hi=L>>4), elems e: W[k = ks*32+hi*8+e][j = nt*16+lo]
// wf1: fid = nt*3+ks (24 frags), wf2: 24 + nt*4+ks (32), wf3: 56 + nt*4+ks (8)
__global__ void k_prep(const float* __restrict__ We1, const float* __restrict__ We2,
                       const float* __restrict__ We3, unsigned short* __restrict__ wf)
{
  int t = blockIdx.x * 256 + threadIdx.x;
  if (t >= 64 * 64) return;
  int fid = t >> 6, lane = t & 63;
  int lo = lane & 15, hi = lane >> 4;
  s16x8 vh, vl;
#pragma unroll
  for (int e = 0; e < 8; ++e) {
    float wv;
    if (fid < 24) {
      int nt = fid / 3, ks = fid % 3;
      wv = We1[(ks * 32 + hi * 8 + e) * 128 + nt * 16 + lo];
    } else if (fid < 56) {
      int f = fid - 24, nt = f >> 2, ks = f & 3;
      wv = We2[(ks * 32 + hi * 8 + e) * 128 + nt * 16 + lo];
    } else {
      int f = fid - 56, nt = f >> 2, ks = f & 3;
      wv = We3[(ks * 32 + hi * 8 + e) * 32 + nt * 16 + lo];
    }
    unsigned short h_, l_;
    splitf(wv, h_, l_);
    vh[e] = (short)h_; vl[e] = (short)l_;
  }
  *(s16x8*)(wf + (size_t)fid * 512 + lane * 8) = vh;
  *(s16x8*)(wf + (size_t)(fid + 64) * 512 + lane * 8) = vl;
}

// ---------------- GRU via MFMA (split precision): 16 paths/block, 2 waves split gate cols ----------------
__global__ __launch_bounds__(128) void k_gru_mfma(
    const float* __restrict__ ls, const float* __restrict__ nsb, float* __restrict__ psb,
    const int* __restrict__ l2p, const int* __restrict__ n2p,
    const float* __restrict__ gk, const float* __restrict__ grk,
    const float* __restrict__ gb, float* __restrict__ ms)
{
  __shared__ __align__(16) unsigned short hbh[2][16][40];
  __shared__ __align__(16) unsigned short hbl[2][16][40];
  const int lane = threadIdx.x & 63;
  const int w = threadIdx.x >> 6;          // wave 0: d 0..15, wave 1: d 16..31
  const int lo = lane & 15, hi = lane >> 4;
  const int pb = blockIdx.x * 16;
  const int d = w * 16 + lo;               // output col within each gate

  // weight B-frags, hi+lo (k = kbase + hi*8 + e, col j)
  s16x8 wz0h, wz0l, wz1h, wz1l, whzh, whzl;
  s16x8 wr0h, wr0l, wr1h, wr1l, whrh, whrl;
  s16x8 wc0h, wc0l, wc1h, wc1l, whch, whcl;
#pragma unroll
  for (int e = 0; e < 8; ++e) {
    int k0 = hi * 8 + e, k1 = 32 + hi * 8 + e;
    unsigned short h_, l_;
    splitf(gk[k0 * 96 + d], h_, l_);       wz0h[e] = (short)h_; wz0l[e] = (short)l_;
    splitf(gk[k1 * 96 + d], h_, l_);       wz1h[e] = (short)h_; wz1l[e] = (short)l_;
    splitf(gk[k0 * 96 + 32 + d], h_, l_);  wr0h[e] = (short)h_; wr0l[e] = (short)l_;
    splitf(gk[k1 * 96 + 32 + d], h_, l_);  wr1h[e] = (short)h_; wr1l[e] = (short)l_;
    splitf(gk[k0 * 96 + 64 + d], h_, l_);  wc0h[e] = (short)h_; wc0l[e] = (short)l_;
    splitf(gk[k1 * 96 + 64 + d], h_, l_);  wc1h[e] = (short)h_; wc1l[e] = (short)l_;
    splitf(grk[k0 * 96 + d], h_, l_);      whzh[e] = (short)h_; whzl[e] = (short)l_;
    splitf(grk[k0 * 96 + 32 + d], h_, l_); whrh[e] = (short)h_; whrl[e] = (short)l_;
    splitf(grk[k0 * 96 + 64 + d], h_, l_); whch[e] = (short)h_; whcl[e] = (short)l_;
  }
  const float bzb = gb[d] + gb[96 + d];
  const float brb = gb[32 + d] + gb[96 + 32 + d];
  const float bcx = gb[64 + d];
  const float bch = gb[96 + 64 + d];

  // h0 in C layout: lane holds rows hi*4+q, col d
  float h[4];
#pragma unroll
  for (int q = 0; q < 4; ++q) {
    h[q] = psb[(size_t)(pb + hi * 4 + q) * 32 + d];
    unsigned short h_, l_;
    splitf(h[q], h_, l_);
    hbh[0][hi * 4 + q][d] = h_;
    hbl[0][hi * 4 + q][d] = l_;
  }
  __syncthreads();
  s16x8 ahh = *(const s16x8*)&hbh[0][lo][hi * 8];
  s16x8 ahl = *(const s16x8*)&hbl[0][lo][hi * 8];

  // x frags for step 0 (A row = lo, k-chunk = hi*8)
  s16x8 ax0h, ax0l, ax1h, ax1l;
  {
    int eA = (pb + lo) * 16;
    const float4* lp = (const float4*)(ls + (size_t)l2p[eA] * 32 + hi * 8);
    const float4* np = (const float4*)(nsb + (size_t)n2p[eA] * 32 + hi * 8);
    pack8s(lp[0], lp[1], ax0h, ax0l);
    pack8s(np[0], np[1], ax1h, ax1l);
  }

  for (int l = 0; l < LL; ++l) {
    s16x8 nx0h, nx0l, nx1h, nx1l;
    if (l + 1 < LL) {  // prefetch next step's gather
      int e2 = (pb + lo) * 16 + l + 1;
      const float4* lp = (const float4*)(ls + (size_t)l2p[e2] * 32 + hi * 8);
      const float4* np = (const float4*)(nsb + (size_t)n2p[e2] * 32 + hi * 8);
      pack8s(lp[0], lp[1], nx0h, nx0l);
      pack8s(np[0], np[1], nx1h, nx1l);
    }
    f32x4 az = {bzb, bzb, bzb, bzb};
    f32x4 ar = {brb, brb, brb, brb};
    f32x4 acx = {bcx, bcx, bcx, bcx};
    f32x4 ach = {bch, bch, bch, bch};
    MM3(az, ax0h, ax0l, wz0h, wz0l);
    MM3(az, ax1h, ax1l, wz1h, wz1l);
    MM3(az, ahh, ahl, whzh, whzl);
    MM3(ar, ax0h, ax0l, wr0h, wr0l);
    MM3(ar, ax1h, ax1l, wr1h, wr1l);
    MM3(ar, ahh, ahl, whrh, whrl);
    MM3(acx, ax0h, ax0l, wc0h, wc0l);
    MM3(acx, ax1h, ax1l, wc1h, wc1l);
    MM3(ach, ahh, ahl, whch, whcl);

    const int ebase = (pb + hi * 4) * 16 + l;
#pragma unroll
    for (int q = 0; q < 4; ++q) {
      float z = sigm(az[q]);
      float r = sigm(ar[q]);
      float c = tanhf_fast(acx[q] + r * ach[q]);
      h[q] = z * h[q] + (1.f - z) * c;
      int link = l2p[ebase + q * 16];
      atomicAdd(ms + (size_t)link * 32 + d, h[q]);
    }
    if (l + 1 < LL) {
      int b = (l + 1) & 1;
#pragma unroll
      for (int q = 0; q < 4; ++q) {
        unsigned short h_, l_;
        splitf(h[q], h_, l_);
        hbh[b][hi * 4 + q][d] = h_;
        hbl[b][hi * 4 + q][d] = l_;
      }
      __syncthreads();
      ahh = *(const s16x8*)&hbh[b][lo][hi * 8];
      ahl = *(const s16x8*)&hbl[b][lo][hi * 8];
      ax0h = nx0h; ax0l = nx0l; ax1h = nx1h; ax1l = nx1l;
    }
  }
#pragma unroll
  for (int q = 0; q < 4; ++q)
    psb[(size_t)(pb + hi * 4 + q) * 32 + d] = h[q];
}

// ---------------- edge MLP via MFMA (split precision): 16 rows per 1-wave block ----------------
__global__ __launch_bounds__(64) void k_mlp_mfma(
    const float* __restrict__ lsi, float* __restrict__ lso,
    const float* __restrict__ nsb, const float* __restrict__ ms,
    const int* __restrict__ l2n, const unsigned short* __restrict__ wf,
    const float* __restrict__ be1, const float* __restrict__ be2, const float* __restrict__ be3)
{
  __shared__ __align__(16) unsigned short abh[4][64][8];
  __shared__ __align__(16) unsigned short abl[4][64][8];
  const int lane = threadIdx.x;
  const int lo = lane & 15, hi = lane >> 4;
  const int row = blockIdx.x * 16 + lo;

  // layer-1 A frags: con = [node(32) | link(32) | m(32)]
  const int nd = l2n[row];
  const float4* a0p = (const float4*)(nsb + (size_t)nd * 32 + hi * 8);
  const float4* a1p = (const float4*)(lsi + (size_t)row * 32 + hi * 8);
  const float4* a2p = (const float4*)(ms + (size_t)row * 32 + hi * 8);
  s16x8 f0h, f0l, f1h, f1l, f2h, f2l;
  pack8s(a0p[0], a0p[1], f0h, f0l);
  pack8s(a1p[0], a1p[1], f1h, f1l);
  pack8s(a2p[0], a2p[1], f2h, f2l);

#define WH(F) (*(const s16x8*)(wf + (size_t)(F) * 512 + lane * 8))
#define WL(F) (*(const s16x8*)(wf + (size_t)((F) + 64) * 512 + lane * 8))

  // layer 1 -> abuf (A-frag order for layer 2)
#pragma unroll
  for (int nt = 0; nt < 8; ++nt) {
    float bias = be1[nt * 16 + lo];
    f32x4 acc = {bias, bias, bias, bias};
    MM3(acc, f0h, f0l, WH(nt * 3 + 0), WL(nt * 3 + 0));
    MM3(acc, f1h, f1l, WH(nt * 3 + 1), WL(nt * 3 + 1));
    MM3(acc, f2h, f2l, WH(nt * 3 + 2), WL(nt * 3 + 2));
#pragma unroll
    for (int q = 0; q < 4; ++q) {
      float v = fmaxf(acc[q], 0.f);
      int rrow = hi * 4 + q, col = nt * 16 + lo;
      unsigned short h_, l_;
      splitf(v, h_, l_);
      abh[col >> 5][rrow + 16 * ((col >> 3) & 3)][col & 7] = h_;
      abl[col >> 5][rrow + 16 * ((col >> 3) & 3)][col & 7] = l_;
    }
  }
  __syncthreads();
  s16x8 x0h = *(const s16x8*)&abh[0][lane][0];
  s16x8 x1h = *(const s16x8*)&abh[1][lane][0];
  s16x8 x2h = *(const s16x8*)&abh[2][lane][0];
  s16x8 x3h = *(const s16x8*)&abh[3][lane][0];
  s16x8 x0l = *(const s16x8*)&abl[0][lane][0];
  s16x8 x1l = *(const s16x8*)&abl[1][lane][0];
  s16x8 x2l = *(const s16x8*)&abl[2][lane][0];
  s16x8 x3l = *(const s16x8*)&abl[3][lane][0];
  __syncthreads();

  // layer 2 -> abuf
#pragma unroll
  for (int nt = 0; nt < 8; ++nt) {
    float bias = be2[nt * 16 + lo];
    f32x4 acc = {bias, bias, bias, bias};
    MM3(acc, x0h, x0l, WH(24 + nt * 4 + 0), WL(24 + nt * 4 + 0));
    MM3(acc, x1h, x1l, WH(24 + nt * 4 + 1), WL(24 + nt * 4 + 1));
    MM3(acc, x2h, x2l, WH(24 + nt * 4 + 2), WL(24 + nt * 4 + 2));
    MM3(acc, x3h, x3l, WH(24 + nt * 4 + 3), WL(24 + nt * 4 + 3));
#pragma unroll
    for (int q = 0; q < 4; ++q) {
      float v = fmaxf(acc[q], 0.f);
      int rrow = hi * 4 + q, col = nt * 16 + lo;
      unsigned short h_, l_;
      splitf(v, h_, l_);
      abh[col >> 5][rrow + 16 * ((col >> 3) & 3)][col & 7] = h_;
      abl[col >> 5][rrow + 16 * ((col >> 3) & 3)][col & 7] = l_;
    }
  }
  __syncthreads();
  x0h = *(const s16x8*)&abh[0][lane][0];
  x1h = *(const s16x8*)&abh[1][lane][0];
  x2h = *(const s16x8*)&abh[2][lane][0];
  x3h = *(const s16x8*)&abh[3][lane][0];
  x0l = *(const s16x8*)&abl[0][lane][0];
  x1l = *(const s16x8*)&abl[1][lane][0];
  x2l = *(const s16x8*)&abl[2][lane][0];
  x3l = *(const s16x8*)&abl[3][lane][0];

  // layer 3 (no relu)
#pragma unroll
  for (int nt = 0; nt < 2; ++nt) {
    float bias = be3[nt * 16 + lo];
    f32x4 acc = {bias, bias, bias, bias};
    MM3(acc, x0h, x0l, WH(56 + nt * 4 + 0), WL(56 + nt * 4 + 0));
    MM3(acc, x1h, x1l, WH(56 + nt * 4 + 1), WL(56 + nt * 4 + 1));
    MM3(acc, x2h, x2l, WH(56 + nt * 4 + 2), WL(56 + nt * 4 + 2));
    MM3(acc, x3h, x3l, WH(56 + nt * 4 + 3), WL(56 + nt * 4 + 3));
#pragma unroll
    for (int q = 0; q < 4; ++q)
      lso[(size_t)(blockIdx.x * 16 + hi * 4 + q) * 32 + nt * 16 + lo] = acc[q];
  }
#undef WH
#undef WL
}

// ---------------- link->node segment sum ----------------
__global__ void k_agg(const float* __restrict__ lsn, const int* __restrict__ l2n,
                      const int* __restrict__ n2l, float* __restrict__ agg)
{
  int id = blockIdx.x * 256 + threadIdx.x;
  if (id >= NLK * 32) return;
  int link = id >> 5, d = id & 31;
  atomicAdd(agg + (size_t)l2n[link] * 32 + d, lsn[(size_t)n2l[link] * 32 + d]);
}

// ---------------- con2 @ Wg -> split-bf16 cw, layout [32][4096] ----------------
__global__ void k_con2w(const float* __restrict__ nsb, const float* __restrict__ agg,
                        const float* __restrict__ Wg,
                        unsigned short* __restrict__ cwbh, unsigned short* __restrict__ cwbl)
{
  int g = blockIdx.x * 256 + threadIdx.x;  // 32*4096
  int d = g >> 12, n = g & 4095;
  float a = 0.f;
#pragma unroll
  for (int i = 0; i < 32; ++i) a = fmaf(nsb[n * 32 + i], Wg[i * 32 + d], a);
#pragma unroll
  for (int i = 0; i < 32; ++i) a = fmaf(agg[n * 32 + i], Wg[(32 + i) * 32 + d], a);
  unsigned short h_, l_;
  splitf(a, h_, l_);
  cwbh[g] = h_;
  cwbl[g] = l_;
}

// ---------------- laplacian @ cw + bg -> node_state, via split-bf16 MFMA ----------------
// block: 16-row tile, 8 waves split K (512 each); LDS cross-wave reduce.
__global__ __launch_bounds__(512) void k_lap_mfma(
    const float* __restrict__ lap, const unsigned short* __restrict__ cwbh,
    const unsigned short* __restrict__ cwbl, const float* __restrict__ bg,
    float* __restrict__ nsb)
{
  __shared__ float red[8][2][64][4];
  const int lane = threadIdx.x & 63;
  const int w = threadIdx.x >> 6;
  const int lo = lane & 15, hi = lane >> 4;
  const int rowbase = blockIdx.x * 16;
  const size_t arow = (size_t)(rowbase + lo) * 4096;
  f32x4 acc0 = {0.f, 0.f, 0.f, 0.f}, acc1 = {0.f, 0.f, 0.f, 0.f};
  const int kb0 = w * 512;
#pragma unroll 4
  for (int ks = 0; ks < 16; ++ks) {
    const int kb = kb0 + ks * 32;
    const float4* ap = (const float4*)(lap + arow + kb + hi * 8);
    s16x8 ah, al;
    pack8s(ap[0], ap[1], ah, al);
    const size_t boff = (size_t)lo * 4096 + kb + hi * 8;
    s16x8 bh0 = *(const s16x8*)(cwbh + boff);
    s16x8 bl0 = *(const s16x8*)(cwbl + boff);
    s16x8 bh1 = *(const s16x8*)(cwbh + boff + 16 * 4096);
    s16x8 bl1 = *(const s16x8*)(cwbl + boff + 16 * 4096);
    MM3(acc0, ah, al, bh0, bl0);
    MM3(acc1, ah, al, bh1, bl1);
  }
  *(f32x4*)&red[w][0][lane][0] = acc0;
  *(f32x4*)&red[w][1][lane][0] = acc1;
  __syncthreads();
  if (w < 2) {
    f32x4 s = {0.f, 0.f, 0.f, 0.f};
#pragma unroll
    for (int ww = 0; ww < 8; ++ww) {
      f32x4 v = *(const f32x4*)&red[ww][w][lane][0];
      s[0] += v[0]; s[1] += v[1]; s[2] += v[2]; s[3] += v[3];
    }
    const float b = bg[w * 16 + lo];
#pragma unroll
    for (int q = 0; q < 4; ++q)
      nsb[(size_t)(rowbase + hi * 4 + q) * 32 + w * 16 + lo] = s[q] + b;
  }
}

// ---------------- readout ----------------
__global__ void k_r1(const float* __restrict__ psb, const float* __restrict__ Wr1,
                     const float* __restrict__ br1, float* __restrict__ r1)
{
  int g = blockIdx.x * 256 + threadIdx.x; // PP*256
  int j = g & 255, p = g >> 8;
  float a = br1[j];
#pragma unroll
  for (int i = 0; i < 32; ++i) a = fmaf(psb[(size_t)p * 32 + i], Wr1[i * 256 + j], a);
  r1[g] = fmaxf(a, 0.f);
}

__global__ void k_r2(const float* __restrict__ r1, const float* __restrict__ Wr2,
                     const float* __restrict__ br2, float* __restrict__ r2)
{
  int g = blockIdx.x * 256 + threadIdx.x; // PP*64
  int p = g >> 6, jt = (g & 63) << 2;
  float a0 = br2[jt], a1 = br2[jt + 1], a2 = br2[jt + 2], a3 = br2[jt + 3];
  const float4* rr = (const float4*)(r1 + (size_t)p * 256);
#pragma unroll 4
  for (int i4 = 0; i4 < 64; ++i4) {
    float4 r = rr[i4];
    const float* wb = Wr2 + (i4 * 4) * 256 + jt;
    float4 w0 = *(const float4*)(wb);
    float4 w1 = *(const float4*)(wb + 256);
    float4 w2 = *(const float4*)(wb + 512);
    float4 w3v = *(const float4*)(wb + 768);
    a0 += r.x * w0.x + r.y * w1.x + r.z * w2.x + r.w * w3v.x;
    a1 += r.x * w0.y + r.y * w1.y + r.z * w2.y + r.w * w3v.y;
    a2 += r.x * w0.z + r.y * w1.z + r.z * w2.z + r.w * w3v.z;
    a3 += r.x * w0.w + r.y * w1.w + r.z * w2.w + r.w * w3v.w;
  }
  *(float4*)(r2 + (size_t)p * 256 + jt) =
      make_float4(fmaxf(a0, 0.f), fmaxf(a1, 0.f), fmaxf(a2, 0.f), fmaxf(a3, 0.f));
}

__global__ void k_out(const float* __restrict__ r2, const float* __restrict__ psb,
                      const float* __restrict__ Wf, const float* __restrict__ bf,
                      float* __restrict__ out)
{
  int p = blockIdx.x * 256 + threadIdx.x;
  if (p >= PP) return;
  float a = bf[0];
  const float4* rr = (const float4*)(r2 + (size_t)p * 256);
  const float4* wf = (const float4*)Wf;
#pragma unroll 8
  for (int i = 0; i < 64; ++i) {
    float4 v = rr[i], w = wf[i];
    a += v.x * w.x + v.y * w.y + v.z * w.z + v.w * w.w;
  }
  const float4* pr = (const float4*)(psb + (size_t)p * 32);
#pragma unroll
  for (int i = 0; i < 8; ++i) {
    float4 v = pr[i], w = wf[64 + i];
    a += v.x * w.x + v.y * w.y + v.z * w.z + v.w * w.w;
  }
  out[p] = a;
}

extern "C" void kernel_launch(void* const* d_in, const int* in_sizes, int n_in,
                              void* d_out, int out_size, void* d_ws, size_t ws_size,
                              hipStream_t stream) {
  const float* capacities = (const float*)d_in[0];
  const float* degrees    = (const float*)d_in[1];
  const float* traffic    = (const float*)d_in[2];
  const float* lap        = (const float*)d_in[3];
  const int*   l2p        = (const int*)d_in[6];
  const int*   n2p        = (const int*)d_in[7];
  const int*   l2n        = (const int*)d_in[8];
  const int*   n2l        = (const int*)d_in[9];
  const float* gk  = (const float*)d_in[13];
  const float* grk = (const float*)d_in[14];
  const float* gb  = (const float*)d_in[15];
  const float* We1 = (const float*)d_in[16]; const float* be1 = (const float*)d_in[17];
  const float* We2 = (const float*)d_in[18]; const float* be2 = (const float*)d_in[19];
  const float* We3 = (const float*)d_in[20]; const float* be3 = (const float*)d_in[21];
  const float* Wg  = (const float*)d_in[22]; const float* bg  = (const float*)d_in[23];
  const float* Wr1 = (const float*)d_in[24]; const float* br1 = (const float*)d_in[25];
  const float* Wr2 = (const float*)d_in[26]; const float* br2 = (const float*)d_in[27];
  const float* Wf  = (const float*)d_in[28]; const float* bf  = (const float*)d_in[29];

  float* w   = (float*)d_ws;
  float* ls0 = w + OFF_LS0;
  float* ls1 = w + OFF_LS1;
  float* nsb = w + OFF_NS;
  float* ms  = w + OFF_MS;
  float* agg = w + OFF_AGG;
  unsigned short* cwbh = (unsigned short*)(w + OFF_CWB);
  unsigned short* cwbl = cwbh + 32 * 4096;
  unsigned short* wfb = (unsigned short*)(w + OFF_WF);
  float* r1  = w + OFF_LS0;   // readout-phase alias over dead iteration buffers
  float* r2  = w + OFF_R2;
  float* psb = w + OFF_PS;

  k_init<<<6250, 256, 0, stream>>>(capacities, degrees, traffic, ls0, nsb, psb);
  k_prep<<<16, 256, 0, stream>>>(We1, We2, We3, wfb);
  for (int t = 0; t < 4; ++t) {
    float* lsi = (t & 1) ? ls1 : ls0;
    float* lso = (t & 1) ? ls0 : ls1;
    hipMemsetAsync(ms, 0, (size_t)NLK * 32 * sizeof(float), stream);
    hipMemsetAsync(agg, 0, (size_t)NNODE * 32 * sizeof(float), stream);
    k_gru_mfma<<<1250, 128, 0, stream>>>(lsi, nsb, psb, l2p, n2p, gk, grk, gb, ms);
    k_mlp_mfma<<<3125, 64, 0, stream>>>(lsi, lso, nsb, ms, l2n, wfb, be1, be2, be3);
    k_agg<<<6250, 256, 0, stream>>>(lso, l2n, n2l, agg);
    k_con2w<<<512, 256, 0, stream>>>(nsb, agg, Wg, cwbh, cwbl);
    k_lap_mfma<<<256, 512, 0, stream>>>(lap, cwbh, cwbl, bg, nsb);
  }
  k_r1<<<20000, 256, 0, stream>>>(psb, Wr1, br1, r1);
  k_r2<<<5000, 256, 0, stream>>>(r1, Wr2, br2, r2);
  k_out<<<79, 256, 0, stream>>>(r2, psb, Wf, bf, (float*)d_out);
}

// Round 6
// 811.915 us; speedup vs baseline: 7.6327x; 1.2630x over previous
//
#include <hip/hip_runtime.h>

#define PP 20000
#define LL 16
#define NLK 50000
#define NNODE 4096

// workspace offsets (in floats)
#define OFF_LS0 0
#define OFF_LS1 1600000
#define OFF_NS  3200000
#define OFF_MS  3331072
#define OFF_AGG 4931072
#define OFF_CWB 5062144   // cw split-bf16: hi [32][4096] ushort, then lo [32][4096] ushort (=131072 floats)
#define OFF_WF  5193216   // frag-ordered bf16 MLP weights hi+lo (65536 ushorts = 32768 floats)
#define OFF_RW  5231104   // frag-ordered bf16 readout weights hi+lo (288 frags * 512 ushorts = 73728 floats)
#define OFF_PS  10351104
// total = 10,991,104 floats = 44.0 MB

typedef __attribute__((ext_vector_type(8))) short s16x8;
typedef __attribute__((ext_vector_type(4))) float f32x4;

__device__ __forceinline__ float sigm(float v) { return 1.f / (1.f + __expf(-v)); }
__device__ __forceinline__ float tanhf_fast(float x) {
  float e = __expf(-2.f * x);
  return 2.f / (1.f + e) - 1.f;
}
__device__ __forceinline__ unsigned short f2bf(float f) {
  unsigned int u = __float_as_uint(f);
  return (unsigned short)((u + 0x7FFFu + ((u >> 16) & 1u)) >> 16);
}
__device__ __forceinline__ float bf2f(unsigned short u) {
  return __uint_as_float(((unsigned int)u) << 16);
}
// split f into hi (bf16 RTN) + lo (bf16 of residual): together ~fp32-accurate
__device__ __forceinline__ void splitf(float f, unsigned short& h, unsigned short& l) {
  unsigned short hh = f2bf(f);
  h = hh;
  l = f2bf(f - bf2f(hh));
}
__device__ __forceinline__ void pack8s(float4 a, float4 b, s16x8& vh, s16x8& vl) {
  float t[8] = {a.x, a.y, a.z, a.w, b.x, b.y, b.z, b.w};
#pragma unroll
  for (int i = 0; i < 8; ++i) {
    unsigned short h_, l_;
    splitf(t[i], h_, l_);
    vh[i] = (short)h_; vl[i] = (short)l_;
  }
}

#define MM(ACC, A, B) ACC = __builtin_amdgcn_mfma_f32_16x16x32_bf16(A, B, ACC, 0, 0, 0)
// full split product: hi*hi + lo*hi + hi*lo
#define MM3(ACC, AH, AL, BH, BL) do { MM(ACC, AH, BH); MM(ACC, AL, BH); MM(ACC, AH, BL); } while (0)

// ---------------- init: states ----------------
__global__ void k_init(const float* __restrict__ cap, const float* __restrict__ deg,
                       const float* __restrict__ traffic,
                       float* __restrict__ ls0, float* __restrict__ nsb, float* __restrict__ psb)
{
  int id = blockIdx.x * 256 + threadIdx.x;
  if (id < NLK * 32) {
    int d = id & 31;
    ls0[id] = (d == 0) ? cap[id >> 5] : 0.f;
  }
  if (id < NNODE * 32) {
    int d = id & 31;
    nsb[id] = (d == 0) ? deg[id >> 5] : 0.f;
  }
  if (id < PP * 32) {
    int d = id & 31, p = id >> 5;
    psb[id] = (d == 0) ? traffic[p] : (d == 1 ? traffic[PP + p] : 0.f);
  }
}

// ---------------- prep: frag-ordered bf16 MLP weights, hi at fid, lo at fid+64 ----------------
// frag f holds, for lane L (lo=L&15, hi=L>>4), elems e: W[k = ks*32+hi*8+e][j = nt*16+lo]
// wf1: fid = nt*3+ks (24 frags), wf2: 24 + nt*4+ks (32), wf3: 56 + nt*4+ks (8)
__global__ void k_prep(const float* __restrict__ We1, const float* __restrict__ We2,
                       const float* __restrict__ We3, unsigned short* __restrict__ wf)
{
  int t = blockIdx.x * 256 + threadIdx.x;
  if (t >= 64 * 64) return;
  int fid = t >> 6, lane = t & 63;
  int lo = lane & 15, hi = lane >> 4;
  s16x8 vh, vl;
#pragma unroll
  for (int e = 0; e < 8; ++e) {
    float wv;
    if (fid < 24) {
      int nt = fid / 3, ks = fid % 3;
      wv = We1[(ks * 32 + hi * 8 + e) * 128 + nt * 16 + lo];
    } else if (fid < 56) {
      int f = fid - 24, nt = f >> 2, ks = f & 3;
      wv = We2[(ks * 32 + hi * 8 + e) * 128 + nt * 16 + lo];
    } else {
      int f = fid - 56, nt = f >> 2, ks = f & 3;
      wv = We3[(ks * 32 + hi * 8 + e) * 32 + nt * 16 + lo];
    }
    unsigned short h_, l_;
    splitf(wv, h_, l_);
    vh[e] = (short)h_; vl[e] = (short)l_;
  }
  *(s16x8*)(wf + (size_t)fid * 512 + lane * 8) = vh;
  *(s16x8*)(wf + (size_t)(fid + 64) * 512 + lane * 8) = vl;
}

// ---------------- prep2: frag-ordered bf16 readout weights ----------------
// Wr1 [32][256]: frag nt (16): hi at nt, lo at nt+16
// Wr2 [256][256]: frag f2 = nt*8+ks (128): hi at 32+f2, lo at 160+f2
__global__ void k_prep2(const float* __restrict__ Wr1, const float* __restrict__ Wr2,
                        unsigned short* __restrict__ rw)
{
  int t = blockIdx.x * 256 + threadIdx.x;
  if (t >= 144 * 64) return;
  int fid = t >> 6, lane = t & 63;
  int lo = lane & 15, hi = lane >> 4;
  s16x8 vh, vl;
  int hbase, lbase;
  if (fid < 16) {
    hbase = fid; lbase = fid + 16;
#pragma unroll
    for (int e = 0; e < 8; ++e) {
      unsigned short h_, l_;
      splitf(Wr1[(hi * 8 + e) * 256 + fid * 16 + lo], h_, l_);
      vh[e] = (short)h_; vl[e] = (short)l_;
    }
  } else {
    int f2 = fid - 16, nt = f2 >> 3, ks = f2 & 7;
    hbase = 32 + f2; lbase = 160 + f2;
#pragma unroll
    for (int e = 0; e < 8; ++e) {
      unsigned short h_, l_;
      splitf(Wr2[(ks * 32 + hi * 8 + e) * 256 + nt * 16 + lo], h_, l_);
      vh[e] = (short)h_; vl[e] = (short)l_;
    }
  }
  *(s16x8*)(rw + (size_t)hbase * 512 + lane * 8) = vh;
  *(s16x8*)(rw + (size_t)lbase * 512 + lane * 8) = vl;
}

// ---------------- GRU via MFMA (split precision): 16 paths/block, 2 waves split gate cols ----------------
__global__ __launch_bounds__(128) void k_gru_mfma(
    const float* __restrict__ ls, const float* __restrict__ nsb, float* __restrict__ psb,
    const int* __restrict__ l2p, const int* __restrict__ n2p,
    const float* __restrict__ gk, const float* __restrict__ grk,
    const float* __restrict__ gb, float* __restrict__ ms)
{
  __shared__ __align__(16) unsigned short hbh[2][16][40];
  __shared__ __align__(16) unsigned short hbl[2][16][40];
  const int lane = threadIdx.x & 63;
  const int w = threadIdx.x >> 6;          // wave 0: d 0..15, wave 1: d 16..31
  const int lo = lane & 15, hi = lane >> 4;
  const int pb = blockIdx.x * 16;
  const int d = w * 16 + lo;               // output col within each gate

  // weight B-frags, hi+lo (k = kbase + hi*8 + e, col j)
  s16x8 wz0h, wz0l, wz1h, wz1l, whzh, whzl;
  s16x8 wr0h, wr0l, wr1h, wr1l, whrh, whrl;
  s16x8 wc0h, wc0l, wc1h, wc1l, whch, whcl;
#pragma unroll
  for (int e = 0; e < 8; ++e) {
    int k0 = hi * 8 + e, k1 = 32 + hi * 8 + e;
    unsigned short h_, l_;
    splitf(gk[k0 * 96 + d], h_, l_);       wz0h[e] = (short)h_; wz0l[e] = (short)l_;
    splitf(gk[k1 * 96 + d], h_, l_);       wz1h[e] = (short)h_; wz1l[e] = (short)l_;
    splitf(gk[k0 * 96 + 32 + d], h_, l_);  wr0h[e] = (short)h_; wr0l[e] = (short)l_;
    splitf(gk[k1 * 96 + 32 + d], h_, l_);  wr1h[e] = (short)h_; wr1l[e] = (short)l_;
    splitf(gk[k0 * 96 + 64 + d], h_, l_);  wc0h[e] = (short)h_; wc0l[e] = (short)l_;
    splitf(gk[k1 * 96 + 64 + d], h_, l_);  wc1h[e] = (short)h_; wc1l[e] = (short)l_;
    splitf(grk[k0 * 96 + d], h_, l_);      whzh[e] = (short)h_; whzl[e] = (short)l_;
    splitf(grk[k0 * 96 + 32 + d], h_, l_); whrh[e] = (short)h_; whrl[e] = (short)l_;
    splitf(grk[k0 * 96 + 64 + d], h_, l_); whch[e] = (short)h_; whcl[e] = (short)l_;
  }
  const float bzb = gb[d] + gb[96 + d];
  const float brb = gb[32 + d] + gb[96 + 32 + d];
  const float bcx = gb[64 + d];
  const float bch = gb[96 + 64 + d];

  // h0 in C layout: lane holds rows hi*4+q, col d
  float h[4];
#pragma unroll
  for (int q = 0; q < 4; ++q) {
    h[q] = psb[(size_t)(pb + hi * 4 + q) * 32 + d];
    unsigned short h_, l_;
    splitf(h[q], h_, l_);
    hbh[0][hi * 4 + q][d] = h_;
    hbl[0][hi * 4 + q][d] = l_;
  }
  __syncthreads();
  s16x8 ahh = *(const s16x8*)&hbh[0][lo][hi * 8];
  s16x8 ahl = *(const s16x8*)&hbl[0][lo][hi * 8];

  // x frags for step 0 (A row = lo, k-chunk = hi*8)
  s16x8 ax0h, ax0l, ax1h, ax1l;
  {
    int eA = (pb + lo) * 16;
    const float4* lp = (const float4*)(ls + (size_t)l2p[eA] * 32 + hi * 8);
    const float4* np = (const float4*)(nsb + (size_t)n2p[eA] * 32 + hi * 8);
    pack8s(lp[0], lp[1], ax0h, ax0l);
    pack8s(np[0], np[1], ax1h, ax1l);
  }

  for (int l = 0; l < LL; ++l) {
    s16x8 nx0h, nx0l, nx1h, nx1l;
    if (l + 1 < LL) {  // prefetch next step's gather
      int e2 = (pb + lo) * 16 + l + 1;
      const float4* lp = (const float4*)(ls + (size_t)l2p[e2] * 32 + hi * 8);
      const float4* np = (const float4*)(nsb + (size_t)n2p[e2] * 32 + hi * 8);
      pack8s(lp[0], lp[1], nx0h, nx0l);
      pack8s(np[0], np[1], nx1h, nx1l);
    }
    f32x4 az = {bzb, bzb, bzb, bzb};
    f32x4 ar = {brb, brb, brb, brb};
    f32x4 acx = {bcx, bcx, bcx, bcx};
    f32x4 ach = {bch, bch, bch, bch};
    MM3(az, ax0h, ax0l, wz0h, wz0l);
    MM3(az, ax1h, ax1l, wz1h, wz1l);
    MM3(az, ahh, ahl, whzh, whzl);
    MM3(ar, ax0h, ax0l, wr0h, wr0l);
    MM3(ar, ax1h, ax1l, wr1h, wr1l);
    MM3(ar, ahh, ahl, whrh, whrl);
    MM3(acx, ax0h, ax0l, wc0h, wc0l);
    MM3(acx, ax1h, ax1l, wc1h, wc1l);
    MM3(ach, ahh, ahl, whch, whcl);

    const int ebase = (pb + hi * 4) * 16 + l;
#pragma unroll
    for (int q = 0; q < 4; ++q) {
      float z = sigm(az[q]);
      float r = sigm(ar[q]);
      float c = tanhf_fast(acx[q] + r * ach[q]);
      h[q] = z * h[q] + (1.f - z) * c;
      int link = l2p[ebase + q * 16];
      atomicAdd(ms + (size_t)link * 32 + d, h[q]);
    }
    if (l + 1 < LL) {
      int b = (l + 1) & 1;
#pragma unroll
      for (int q = 0; q < 4; ++q) {
        unsigned short h_, l_;
        splitf(h[q], h_, l_);
        hbh[b][hi * 4 + q][d] = h_;
        hbl[b][hi * 4 + q][d] = l_;
      }
      __syncthreads();
      ahh = *(const s16x8*)&hbh[b][lo][hi * 8];
      ahl = *(const s16x8*)&hbl[b][lo][hi * 8];
      ax0h = nx0h; ax0l = nx0l; ax1h = nx1h; ax1l = nx1l;
    }
  }
#pragma unroll
  for (int q = 0; q < 4; ++q)
    psb[(size_t)(pb + hi * 4 + q) * 32 + d] = h[q];
}

// ---------------- edge MLP via MFMA (split precision): 16 rows per 1-wave block ----------------
__global__ __launch_bounds__(64) void k_mlp_mfma(
    const float* __restrict__ lsi, float* __restrict__ lso,
    const float* __restrict__ nsb, const float* __restrict__ ms,
    const int* __restrict__ l2n, const unsigned short* __restrict__ wf,
    const float* __restrict__ be1, const float* __restrict__ be2, const float* __restrict__ be3)
{
  __shared__ __align__(16) unsigned short abh[4][64][8];
  __shared__ __align__(16) unsigned short abl[4][64][8];
  const int lane = threadIdx.x;
  const int lo = lane & 15, hi = lane >> 4;
  const int row = blockIdx.x * 16 + lo;

  // layer-1 A frags: con = [node(32) | link(32) | m(32)]
  const int nd = l2n[row];
  const float4* a0p = (const float4*)(nsb + (size_t)nd * 32 + hi * 8);
  const float4* a1p = (const float4*)(lsi + (size_t)row * 32 + hi * 8);
  const float4* a2p = (const float4*)(ms + (size_t)row * 32 + hi * 8);
  s16x8 f0h, f0l, f1h, f1l, f2h, f2l;
  pack8s(a0p[0], a0p[1], f0h, f0l);
  pack8s(a1p[0], a1p[1], f1h, f1l);
  pack8s(a2p[0], a2p[1], f2h, f2l);

#define WH(F) (*(const s16x8*)(wf + (size_t)(F) * 512 + lane * 8))
#define WL(F) (*(const s16x8*)(wf + (size_t)((F) + 64) * 512 + lane * 8))

  // layer 1 -> abuf (A-frag order for layer 2)
#pragma unroll
  for (int nt = 0; nt < 8; ++nt) {
    float bias = be1[nt * 16 + lo];
    f32x4 acc = {bias, bias, bias, bias};
    MM3(acc, f0h, f0l, WH(nt * 3 + 0), WL(nt * 3 + 0));
    MM3(acc, f1h, f1l, WH(nt * 3 + 1), WL(nt * 3 + 1));
    MM3(acc, f2h, f2l, WH(nt * 3 + 2), WL(nt * 3 + 2));
#pragma unroll
    for (int q = 0; q < 4; ++q) {
      float v = fmaxf(acc[q], 0.f);
      int rrow = hi * 4 + q, col = nt * 16 + lo;
      unsigned short h_, l_;
      splitf(v, h_, l_);
      abh[col >> 5][rrow + 16 * ((col >> 3) & 3)][col & 7] = h_;
      abl[col >> 5][rrow + 16 * ((col >> 3) & 3)][col & 7] = l_;
    }
  }
  __syncthreads();
  s16x8 x0h = *(const s16x8*)&abh[0][lane][0];
  s16x8 x1h = *(const s16x8*)&abh[1][lane][0];
  s16x8 x2h = *(const s16x8*)&abh[2][lane][0];
  s16x8 x3h = *(const s16x8*)&abh[3][lane][0];
  s16x8 x0l = *(const s16x8*)&abl[0][lane][0];
  s16x8 x1l = *(const s16x8*)&abl[1][lane][0];
  s16x8 x2l = *(const s16x8*)&abl[2][lane][0];
  s16x8 x3l = *(const s16x8*)&abl[3][lane][0];
  __syncthreads();

  // layer 2 -> abuf
#pragma unroll
  for (int nt = 0; nt < 8; ++nt) {
    float bias = be2[nt * 16 + lo];
    f32x4 acc = {bias, bias, bias, bias};
    MM3(acc, x0h, x0l, WH(24 + nt * 4 + 0), WL(24 + nt * 4 + 0));
    MM3(acc, x1h, x1l, WH(24 + nt * 4 + 1), WL(24 + nt * 4 + 1));
    MM3(acc, x2h, x2l, WH(24 + nt * 4 + 2), WL(24 + nt * 4 + 2));
    MM3(acc, x3h, x3l, WH(24 + nt * 4 + 3), WL(24 + nt * 4 + 3));
#pragma unroll
    for (int q = 0; q < 4; ++q) {
      float v = fmaxf(acc[q], 0.f);
      int rrow = hi * 4 + q, col = nt * 16 + lo;
      unsigned short h_, l_;
      splitf(v, h_, l_);
      abh[col >> 5][rrow + 16 * ((col >> 3) & 3)][col & 7] = h_;
      abl[col >> 5][rrow + 16 * ((col >> 3) & 3)][col & 7] = l_;
    }
  }
  __syncthreads();
  x0h = *(const s16x8*)&abh[0][lane][0];
  x1h = *(const s16x8*)&abh[1][lane][0];
  x2h = *(const s16x8*)&abh[2][lane][0];
  x3h = *(const s16x8*)&abh[3][lane][0];
  x0l = *(const s16x8*)&abl[0][lane][0];
  x1l = *(const s16x8*)&abl[1][lane][0];
  x2l = *(const s16x8*)&abl[2][lane][0];
  x3l = *(const s16x8*)&abl[3][lane][0];

  // layer 3 (no relu)
#pragma unroll
  for (int nt = 0; nt < 2; ++nt) {
    float bias = be3[nt * 16 + lo];
    f32x4 acc = {bias, bias, bias, bias};
    MM3(acc, x0h, x0l, WH(56 + nt * 4 + 0), WL(56 + nt * 4 + 0));
    MM3(acc, x1h, x1l, WH(56 + nt * 4 + 1), WL(56 + nt * 4 + 1));
    MM3(acc, x2h, x2l, WH(56 + nt * 4 + 2), WL(56 + nt * 4 + 2));
    MM3(acc, x3h, x3l, WH(56 + nt * 4 + 3), WL(56 + nt * 4 + 3));
#pragma unroll
    for (int q = 0; q < 4; ++q)
      lso[(size_t)(blockIdx.x * 16 + hi * 4 + q) * 32 + nt * 16 + lo] = acc[q];
  }
#undef WH
#undef WL
}

// ---------------- link->node segment sum ----------------
__global__ void k_agg(const float* __restrict__ lsn, const int* __restrict__ l2n,
                      const int* __restrict__ n2l, float* __restrict__ agg)
{
  int id = blockIdx.x * 256 + threadIdx.x;
  if (id >= NLK * 32) return;
  int link = id >> 5, d = id & 31;
  atomicAdd(agg + (size_t)l2n[link] * 32 + d, lsn[(size_t)n2l[link] * 32 + d]);
}

// ---------------- con2 @ Wg -> split-bf16 cw, layout [32][4096] ----------------
__global__ void k_con2w(const float* __restrict__ nsb, const float* __restrict__ agg,
                        const float* __restrict__ Wg,
                        unsigned short* __restrict__ cwbh, unsigned short* __restrict__ cwbl)
{
  int g = blockIdx.x * 256 + threadIdx.x;  // 32*4096
  int d = g >> 12, n = g & 4095;
  float a = 0.f;
#pragma unroll
  for (int i = 0; i < 32; ++i) a = fmaf(nsb[n * 32 + i], Wg[i * 32 + d], a);
#pragma unroll
  for (int i = 0; i < 32; ++i) a = fmaf(agg[n * 32 + i], Wg[(32 + i) * 32 + d], a);
  unsigned short h_, l_;
  splitf(a, h_, l_);
  cwbh[g] = h_;
  cwbl[g] = l_;
}

// ---------------- laplacian @ cw + bg -> node_state, via split-bf16 MFMA ----------------
// block: 16-row tile, 8 waves split K (512 each); LDS cross-wave reduce.
__global__ __launch_bounds__(512) void k_lap_mfma(
    const float* __restrict__ lap, const unsigned short* __restrict__ cwbh,
    const unsigned short* __restrict__ cwbl, const float* __restrict__ bg,
    float* __restrict__ nsb)
{
  __shared__ float red[8][2][64][4];
  const int lane = threadIdx.x & 63;
  const int w = threadIdx.x >> 6;
  const int lo = lane & 15, hi = lane >> 4;
  const int rowbase = blockIdx.x * 16;
  const size_t arow = (size_t)(rowbase + lo) * 4096;
  f32x4 acc0 = {0.f, 0.f, 0.f, 0.f}, acc1 = {0.f, 0.f, 0.f, 0.f};
  const int kb0 = w * 512;
#pragma unroll 4
  for (int ks = 0; ks < 16; ++ks) {
    const int kb = kb0 + ks * 32;
    const float4* ap = (const float4*)(lap + arow + kb + hi * 8);
    s16x8 ah, al;
    pack8s(ap[0], ap[1], ah, al);
    const size_t boff = (size_t)lo * 4096 + kb + hi * 8;
    s16x8 bh0 = *(const s16x8*)(cwbh + boff);
    s16x8 bl0 = *(const s16x8*)(cwbl + boff);
    s16x8 bh1 = *(const s16x8*)(cwbh + boff + 16 * 4096);
    s16x8 bl1 = *(const s16x8*)(cwbl + boff + 16 * 4096);
    MM3(acc0, ah, al, bh0, bl0);
    MM3(acc1, ah, al, bh1, bl1);
  }
  *(f32x4*)&red[w][0][lane][0] = acc0;
  *(f32x4*)&red[w][1][lane][0] = acc1;
  __syncthreads();
  if (w < 2) {
    f32x4 s = {0.f, 0.f, 0.f, 0.f};
#pragma unroll
    for (int ww = 0; ww < 8; ++ww) {
      f32x4 v = *(const f32x4*)&red[ww][w][lane][0];
      s[0] += v[0]; s[1] += v[1]; s[2] += v[2]; s[3] += v[3];
    }
    const float b = bg[w * 16 + lo];
#pragma unroll
    for (int q = 0; q < 4; ++q)
      nsb[(size_t)(rowbase + hi * 4 + q) * 32 + w * 16 + lo] = s[q] + b;
  }
}

// ---------------- fused readout: r1 -> r2 -> out, 16 paths/block, 4 waves ----------------
// wave w owns col-tiles nt = w*4 .. w*4+3 for both r1 and r2.
__global__ __launch_bounds__(256) void k_read(
    const float* __restrict__ psb, const unsigned short* __restrict__ rw,
    const float* __restrict__ br1, const float* __restrict__ br2,
    const float* __restrict__ Wf, const float* __restrict__ bf,
    float* __restrict__ out)
{
  __shared__ __align__(16) unsigned short r1h[8][64][8];
  __shared__ __align__(16) unsigned short r1l[8][64][8];
  __shared__ float red[4][4][4];
  const int lane = threadIdx.x & 63;
  const int w = threadIdx.x >> 6;
  const int lo = lane & 15, hi = lane >> 4;
  const int pb = blockIdx.x * 16;

#define RH1(NT) (*(const s16x8*)(rw + (size_t)(NT) * 512 + lane * 8))
#define RL1(NT) (*(const s16x8*)(rw + (size_t)((NT) + 16) * 512 + lane * 8))
#define RH2(NT, KS) (*(const s16x8*)(rw + (size_t)(32 + (NT) * 8 + (KS)) * 512 + lane * 8))
#define RL2(NT, KS) (*(const s16x8*)(rw + (size_t)(160 + (NT) * 8 + (KS)) * 512 + lane * 8))

  // A-frag from psb: row = lo, k = hi*8+e
  s16x8 pAh, pAl;
  {
    const float4* pp = (const float4*)(psb + (size_t)(pb + lo) * 32 + hi * 8);
    pack8s(pp[0], pp[1], pAh, pAl);
  }

  // layer 1: r1 = relu(psb @ Wr1 + br1), staged to LDS in A-frag order
#pragma unroll
  for (int j = 0; j < 4; ++j) {
    const int nt = w * 4 + j;
    float bias = br1[nt * 16 + lo];
    f32x4 acc = {bias, bias, bias, bias};
    MM3(acc, pAh, pAl, RH1(nt), RL1(nt));
#pragma unroll
    for (int q = 0; q < 4; ++q) {
      float v = fmaxf(acc[q], 0.f);
      int rrow = hi * 4 + q, col = nt * 16 + lo;
      unsigned short h_, l_;
      splitf(v, h_, l_);
      r1h[col >> 5][rrow + 16 * ((col >> 3) & 3)][col & 7] = h_;
      r1l[col >> 5][rrow + 16 * ((col >> 3) & 3)][col & 7] = l_;
    }
  }
  __syncthreads();

  s16x8 xh[8], xl[8];
#pragma unroll
  for (int ks = 0; ks < 8; ++ks) {
    xh[ks] = *(const s16x8*)&r1h[ks][lane][0];
    xl[ks] = *(const s16x8*)&r1l[ks][lane][0];
  }

  // layer 2 + in-register Wf dot: partial[q] = sum over this wave's cols
  float partial[4] = {0.f, 0.f, 0.f, 0.f};
#pragma unroll
  for (int j = 0; j < 4; ++j) {
    const int nt = w * 4 + j;
    float bias = br2[nt * 16 + lo];
    f32x4 acc = {bias, bias, bias, bias};
#pragma unroll
    for (int ks = 0; ks < 8; ++ks)
      MM3(acc, xh[ks], xl[ks], RH2(nt, ks), RL2(nt, ks));
    const float wfv = Wf[nt * 16 + lo];
#pragma unroll
    for (int q = 0; q < 4; ++q)
      partial[q] = fmaf(fmaxf(acc[q], 0.f), wfv, partial[q]);
  }
  // reduce across the 16 lo lanes (lane bits 0..3)
#pragma unroll
  for (int m = 1; m <= 8; m <<= 1) {
#pragma unroll
    for (int q = 0; q < 4; ++q) partial[q] += __shfl_xor(partial[q], m);
  }
  if (lo == 0) {
#pragma unroll
    for (int q = 0; q < 4; ++q) red[w][hi][q] = partial[q];
  }
  __syncthreads();
  if (threadIdx.x < 16) {
    const int row = threadIdx.x, h2 = row >> 2, q2 = row & 3;
    float s = red[0][h2][q2] + red[1][h2][q2] + red[2][h2][q2] + red[3][h2][q2] + bf[0];
    const float4* pr = (const float4*)(psb + (size_t)(pb + row) * 32);
    const float4* wt = (const float4*)(Wf + 256);
#pragma unroll
    for (int i = 0; i < 8; ++i) {
      float4 v = pr[i], t = wt[i];
      s += v.x * t.x + v.y * t.y + v.z * t.z + v.w * t.w;
    }
    out[pb + row] = s;
  }
#undef RH1
#undef RL1
#undef RH2
#undef RL2
}

extern "C" void kernel_launch(void* const* d_in, const int* in_sizes, int n_in,
                              void* d_out, int out_size, void* d_ws, size_t ws_size,
                              hipStream_t stream) {
  const float* capacities = (const float*)d_in[0];
  const float* degrees    = (const float*)d_in[1];
  const float* traffic    = (const float*)d_in[2];
  const float* lap        = (const float*)d_in[3];
  const int*   l2p        = (const int*)d_in[6];
  const int*   n2p        = (const int*)d_in[7];
  const int*   l2n        = (const int*)d_in[8];
  const int*   n2l        = (const int*)d_in[9];
  const float* gk  = (const float*)d_in[13];
  const float* grk = (const float*)d_in[14];
  const float* gb  = (const float*)d_in[15];
  const float* We1 = (const float*)d_in[16]; const float* be1 = (const float*)d_in[17];
  const float* We2 = (const float*)d_in[18]; const float* be2 = (const float*)d_in[19];
  const float* We3 = (const float*)d_in[20]; const float* be3 = (const float*)d_in[21];
  const float* Wg  = (const float*)d_in[22]; const float* bg  = (const float*)d_in[23];
  const float* Wr1 = (const float*)d_in[24]; const float* br1 = (const float*)d_in[25];
  const float* Wr2 = (const float*)d_in[26]; const float* br2 = (const float*)d_in[27];
  const float* Wf  = (const float*)d_in[28]; const float* bf  = (const float*)d_in[29];

  float* w   = (float*)d_ws;
  float* ls0 = w + OFF_LS0;
  float* ls1 = w + OFF_LS1;
  float* nsb = w + OFF_NS;
  float* ms  = w + OFF_MS;
  float* agg = w + OFF_AGG;
  unsigned short* cwbh = (unsigned short*)(w + OFF_CWB);
  unsigned short* cwbl = cwbh + 32 * 4096;
  unsigned short* wfb = (unsigned short*)(w + OFF_WF);
  unsigned short* rwb = (unsigned short*)(w + OFF_RW);
  float* psb = w + OFF_PS;

  k_init<<<6250, 256, 0, stream>>>(capacities, degrees, traffic, ls0, nsb, psb);
  k_prep<<<16, 256, 0, stream>>>(We1, We2, We3, wfb);
  k_prep2<<<36, 256, 0, stream>>>(Wr1, Wr2, rwb);
  for (int t = 0; t < 4; ++t) {
    float* lsi = (t & 1) ? ls1 : ls0;
    float* lso = (t & 1) ? ls0 : ls1;
    hipMemsetAsync(ms, 0, (size_t)NLK * 32 * sizeof(float), stream);
    hipMemsetAsync(agg, 0, (size_t)NNODE * 32 * sizeof(float), stream);
    k_gru_mfma<<<1250, 128, 0, stream>>>(lsi, nsb, psb, l2p, n2p, gk, grk, gb, ms);
    k_mlp_mfma<<<3125, 64, 0, stream>>>(lsi, lso, nsb, ms, l2n, wfb, be1, be2, be3);
    k_agg<<<6250, 256, 0, stream>>>(lso, l2n, n2l, agg);
    k_con2w<<<512, 256, 0, stream>>>(nsb, agg, Wg, cwbh, cwbl);
    k_lap_mfma<<<256, 512, 0, stream>>>(lap, cwbh, cwbl, bg, nsb);
  }
  k_read<<<1250, 256, 0, stream>>>(psb, rwb, br1, br2, Wf, bf, (float*)d_out);
}

// Round 7
// 618.251 us; speedup vs baseline: 10.0236x; 1.3132x over previous
//
#include <hip/hip_runtime.h>

#define PP 20000
#define LL 16
#define NLK 50000
#define NNODE 4096

// workspace offsets (in floats)
#define OFF_LSH0 0         // link state hi, buf0: NLK*32 ushort = 800000 floats
#define OFF_LSL0 800000
#define OFF_LSH1 1600000
#define OFF_LSL1 2400000
#define OFF_MS   3200000   // fp32 segment-sum accumulator, 1600000 floats
#define OFF_AGG  4800000   // fp32, 131072
#define OFF_NSH  4931072   // node state hi: NNODE*32 ushort = 65536 floats
#define OFF_NSL  4996608
#define OFF_CWB  5062144   // cw split-bf16 hi+lo (131072 floats)
#define OFF_WF   5193216   // frag-ordered MLP weights hi+lo (32768 floats)
#define OFF_RW   5225984   // frag-ordered readout weights hi+lo (73728 floats)
#define OFF_PS   5299712   // path state fp32, 640000 floats
// total = 5,939,712 floats = 23.8 MB

typedef __attribute__((ext_vector_type(8))) short s16x8;
typedef __attribute__((ext_vector_type(4))) float f32x4;

__device__ __forceinline__ float sigm(float v) { return 1.f / (1.f + __expf(-v)); }
__device__ __forceinline__ float tanhf_fast(float x) {
  float e = __expf(-2.f * x);
  return 2.f / (1.f + e) - 1.f;
}
__device__ __forceinline__ unsigned short f2bf(float f) {
  unsigned int u = __float_as_uint(f);
  return (unsigned short)((u + 0x7FFFu + ((u >> 16) & 1u)) >> 16);
}
__device__ __forceinline__ float bf2f(unsigned short u) {
  return __uint_as_float(((unsigned int)u) << 16);
}
// split f into hi (bf16 RTN) + lo (bf16 of residual): together ~fp32-accurate
__device__ __forceinline__ void splitf(float f, unsigned short& h, unsigned short& l) {
  unsigned short hh = f2bf(f);
  h = hh;
  l = f2bf(f - bf2f(hh));
}
__device__ __forceinline__ void pack8s(float4 a, float4 b, s16x8& vh, s16x8& vl) {
  float t[8] = {a.x, a.y, a.z, a.w, b.x, b.y, b.z, b.w};
#pragma unroll
  for (int i = 0; i < 8; ++i) {
    unsigned short h_, l_;
    splitf(t[i], h_, l_);
    vh[i] = (short)h_; vl[i] = (short)l_;
  }
}

#define MM(ACC, A, B) ACC = __builtin_amdgcn_mfma_f32_16x16x32_bf16(A, B, ACC, 0, 0, 0)
// full split product: hi*hi + lo*hi + hi*lo
#define MM3(ACC, AH, AL, BH, BL) do { MM(ACC, AH, BH); MM(ACC, AL, BH); MM(ACC, AH, BL); } while (0)

// ---------------- init: states (split bf16 for link/node, fp32 for path) ----------------
__global__ void k_init(const float* __restrict__ cap, const float* __restrict__ deg,
                       const float* __restrict__ traffic,
                       unsigned short* __restrict__ lsh, unsigned short* __restrict__ lsl,
                       unsigned short* __restrict__ nsh, unsigned short* __restrict__ nsl,
                       float* __restrict__ psb)
{
  int id = blockIdx.x * 256 + threadIdx.x;
  if (id < NLK * 32) {
    int d = id & 31;
    unsigned short h_ = 0, l_ = 0;
    if (d == 0) splitf(cap[id >> 5], h_, l_);
    lsh[id] = h_; lsl[id] = l_;
  }
  if (id < NNODE * 32) {
    int d = id & 31;
    unsigned short h_ = 0, l_ = 0;
    if (d == 0) splitf(deg[id >> 5], h_, l_);
    nsh[id] = h_; nsl[id] = l_;
  }
  if (id < PP * 32) {
    int d = id & 31, p = id >> 5;
    psb[id] = (d == 0) ? traffic[p] : (d == 1 ? traffic[PP + p] : 0.f);
  }
}

// ---------------- prep: frag-ordered bf16 MLP weights, hi at fid, lo at fid+64 ----------------
__global__ void k_prep(const float* __restrict__ We1, const float* __restrict__ We2,
                       const float* __restrict__ We3, unsigned short* __restrict__ wf)
{
  int t = blockIdx.x * 256 + threadIdx.x;
  if (t >= 64 * 64) return;
  int fid = t >> 6, lane = t & 63;
  int lo = lane & 15, hi = lane >> 4;
  s16x8 vh, vl;
#pragma unroll
  for (int e = 0; e < 8; ++e) {
    float wv;
    if (fid < 24) {
      int nt = fid / 3, ks = fid % 3;
      wv = We1[(ks * 32 + hi * 8 + e) * 128 + nt * 16 + lo];
    } else if (fid < 56) {
      int f = fid - 24, nt = f >> 2, ks = f & 3;
      wv = We2[(ks * 32 + hi * 8 + e) * 128 + nt * 16 + lo];
    } else {
      int f = fid - 56, nt = f >> 2, ks = f & 3;
      wv = We3[(ks * 32 + hi * 8 + e) * 32 + nt * 16 + lo];
    }
    unsigned short h_, l_;
    splitf(wv, h_, l_);
    vh[e] = (short)h_; vl[e] = (short)l_;
  }
  *(s16x8*)(wf + (size_t)fid * 512 + lane * 8) = vh;
  *(s16x8*)(wf + (size_t)(fid + 64) * 512 + lane * 8) = vl;
}

// ---------------- prep2: frag-ordered bf16 readout weights ----------------
__global__ void k_prep2(const float* __restrict__ Wr1, const float* __restrict__ Wr2,
                        unsigned short* __restrict__ rw)
{
  int t = blockIdx.x * 256 + threadIdx.x;
  if (t >= 144 * 64) return;
  int fid = t >> 6, lane = t & 63;
  int lo = lane & 15, hi = lane >> 4;
  s16x8 vh, vl;
  int hbase, lbase;
  if (fid < 16) {
    hbase = fid; lbase = fid + 16;
#pragma unroll
    for (int e = 0; e < 8; ++e) {
      unsigned short h_, l_;
      splitf(Wr1[(hi * 8 + e) * 256 + fid * 16 + lo], h_, l_);
      vh[e] = (short)h_; vl[e] = (short)l_;
    }
  } else {
    int f2 = fid - 16, nt = f2 >> 3, ks = f2 & 7;
    hbase = 32 + f2; lbase = 160 + f2;
#pragma unroll
    for (int e = 0; e < 8; ++e) {
      unsigned short h_, l_;
      splitf(Wr2[(ks * 32 + hi * 8 + e) * 256 + nt * 16 + lo], h_, l_);
      vh[e] = (short)h_; vl[e] = (short)l_;
    }
  }
  *(s16x8*)(rw + (size_t)hbase * 512 + lane * 8) = vh;
  *(s16x8*)(rw + (size_t)lbase * 512 + lane * 8) = vl;
}

// ---------------- GRU via MFMA (split precision): 16 paths/block, 2 waves split gate cols ----
// x-frags load directly from pre-split states (no repack); ms atomics deferred one step so the
// barrier's vmcnt(0) drain overlaps the next step's MFMA+gate work.
__global__ __launch_bounds__(128) void k_gru_mfma(
    const unsigned short* __restrict__ lsh, const unsigned short* __restrict__ lsl,
    const unsigned short* __restrict__ nsh, const unsigned short* __restrict__ nsl,
    float* __restrict__ psb,
    const int* __restrict__ l2p, const int* __restrict__ n2p,
    const float* __restrict__ gk, const float* __restrict__ grk,
    const float* __restrict__ gb, float* __restrict__ ms)
{
  __shared__ __align__(16) unsigned short hbh[2][16][40];
  __shared__ __align__(16) unsigned short hbl[2][16][40];
  const int lane = threadIdx.x & 63;
  const int w = threadIdx.x >> 6;          // wave 0: d 0..15, wave 1: d 16..31
  const int lo = lane & 15, hi = lane >> 4;
  const int pb = blockIdx.x * 16;
  const int d = w * 16 + lo;               // output col within each gate

  // weight B-frags, hi+lo (k = kbase + hi*8 + e, col j)
  s16x8 wz0h, wz0l, wz1h, wz1l, whzh, whzl;
  s16x8 wr0h, wr0l, wr1h, wr1l, whrh, whrl;
  s16x8 wc0h, wc0l, wc1h, wc1l, whch, whcl;
#pragma unroll
  for (int e = 0; e < 8; ++e) {
    int k0 = hi * 8 + e, k1 = 32 + hi * 8 + e;
    unsigned short h_, l_;
    splitf(gk[k0 * 96 + d], h_, l_);       wz0h[e] = (short)h_; wz0l[e] = (short)l_;
    splitf(gk[k1 * 96 + d], h_, l_);       wz1h[e] = (short)h_; wz1l[e] = (short)l_;
    splitf(gk[k0 * 96 + 32 + d], h_, l_);  wr0h[e] = (short)h_; wr0l[e] = (short)l_;
    splitf(gk[k1 * 96 + 32 + d], h_, l_);  wr1h[e] = (short)h_; wr1l[e] = (short)l_;
    splitf(gk[k0 * 96 + 64 + d], h_, l_);  wc0h[e] = (short)h_; wc0l[e] = (short)l_;
    splitf(gk[k1 * 96 + 64 + d], h_, l_);  wc1h[e] = (short)h_; wc1l[e] = (short)l_;
    splitf(grk[k0 * 96 + d], h_, l_);      whzh[e] = (short)h_; whzl[e] = (short)l_;
    splitf(grk[k0 * 96 + 32 + d], h_, l_); whrh[e] = (short)h_; whrl[e] = (short)l_;
    splitf(grk[k0 * 96 + 64 + d], h_, l_); whch[e] = (short)h_; whcl[e] = (short)l_;
  }
  const float bzb = gb[d] + gb[96 + d];
  const float brb = gb[32 + d] + gb[96 + 32 + d];
  const float bcx = gb[64 + d];
  const float bch = gb[96 + 64 + d];

  // h0 in C layout: lane holds rows hi*4+q, col d
  float h[4];
#pragma unroll
  for (int q = 0; q < 4; ++q) {
    h[q] = psb[(size_t)(pb + hi * 4 + q) * 32 + d];
    unsigned short h_, l_;
    splitf(h[q], h_, l_);
    hbh[0][hi * 4 + q][d] = h_;
    hbl[0][hi * 4 + q][d] = l_;
  }
  __syncthreads();
  s16x8 ahh = *(const s16x8*)&hbh[0][lo][hi * 8];
  s16x8 ahl = *(const s16x8*)&hbl[0][lo][hi * 8];

  // x frags for step 0: direct split loads (A row = lo, k-chunk = hi*8)
  s16x8 ax0h, ax0l, ax1h, ax1l;
  {
    int eA = (pb + lo) * 16;
    size_t li = (size_t)l2p[eA] * 32 + hi * 8;
    size_t ni = (size_t)n2p[eA] * 32 + hi * 8;
    ax0h = *(const s16x8*)(lsh + li);
    ax0l = *(const s16x8*)(lsl + li);
    ax1h = *(const s16x8*)(nsh + ni);
    ax1l = *(const s16x8*)(nsl + ni);
  }

  int lka[4];  // link indices for the CURRENT step's h (atomics issued next step)
  for (int l = 0; l < LL; ++l) {
    s16x8 nx0h, nx0l, nx1h, nx1l;
    if (l + 1 < LL) {  // prefetch next step's gather (pure loads, no repack)
      int e2 = (pb + lo) * 16 + l + 1;
      size_t li = (size_t)l2p[e2] * 32 + hi * 8;
      size_t ni = (size_t)n2p[e2] * 32 + hi * 8;
      nx0h = *(const s16x8*)(lsh + li);
      nx0l = *(const s16x8*)(lsl + li);
      nx1h = *(const s16x8*)(nsh + ni);
      nx1l = *(const s16x8*)(nsl + ni);
    }
    // deferred atomics for previous step's h (h regs still hold h_{l-1} here)
    if (l > 0) {
#pragma unroll
      for (int q = 0; q < 4; ++q)
        atomicAdd(ms + (size_t)lka[q] * 32 + d, h[q]);
    }
    // prefetch this step's link indices (used next iteration / post-loop)
#pragma unroll
    for (int q = 0; q < 4; ++q)
      lka[q] = l2p[(pb + hi * 4 + q) * 16 + l];

    f32x4 az = {bzb, bzb, bzb, bzb};
    f32x4 ar = {brb, brb, brb, brb};
    f32x4 acx = {bcx, bcx, bcx, bcx};
    f32x4 ach = {bch, bch, bch, bch};
    MM3(az, ax0h, ax0l, wz0h, wz0l);
    MM3(az, ax1h, ax1l, wz1h, wz1l);
    MM3(az, ahh, ahl, whzh, whzl);
    MM3(ar, ax0h, ax0l, wr0h, wr0l);
    MM3(ar, ax1h, ax1l, wr1h, wr1l);
    MM3(ar, ahh, ahl, whrh, whrl);
    MM3(acx, ax0h, ax0l, wc0h, wc0l);
    MM3(acx, ax1h, ax1l, wc1h, wc1l);
    MM3(ach, ahh, ahl, whch, whcl);

#pragma unroll
    for (int q = 0; q < 4; ++q) {
      float z = sigm(az[q]);
      float r = sigm(ar[q]);
      float c = tanhf_fast(acx[q] + r * ach[q]);
      h[q] = z * h[q] + (1.f - z) * c;
    }
    if (l + 1 < LL) {
      int b = (l + 1) & 1;
#pragma unroll
      for (int q = 0; q < 4; ++q) {
        unsigned short h_, l_;
        splitf(h[q], h_, l_);
        hbh[b][hi * 4 + q][d] = h_;
        hbl[b][hi * 4 + q][d] = l_;
      }
      __syncthreads();
      ahh = *(const s16x8*)&hbh[b][lo][hi * 8];
      ahl = *(const s16x8*)&hbl[b][lo][hi * 8];
      ax0h = nx0h; ax0l = nx0l; ax1h = nx1h; ax1l = nx1l;
    }
  }
  // final step's atomics
#pragma unroll
  for (int q = 0; q < 4; ++q)
    atomicAdd(ms + (size_t)lka[q] * 32 + d, h[q]);
#pragma unroll
  for (int q = 0; q < 4; ++q)
    psb[(size_t)(pb + hi * 4 + q) * 32 + d] = h[q];
}

// ---------------- edge MLP via MFMA (split precision): 16 rows per 1-wave block ----------------
__global__ __launch_bounds__(64) void k_mlp_mfma(
    const unsigned short* __restrict__ lsih, const unsigned short* __restrict__ lsil,
    unsigned short* __restrict__ lsoh, unsigned short* __restrict__ lsol,
    const unsigned short* __restrict__ nsh, const unsigned short* __restrict__ nsl,
    const float* __restrict__ ms,
    const int* __restrict__ l2n, const unsigned short* __restrict__ wf,
    const float* __restrict__ be1, const float* __restrict__ be2, const float* __restrict__ be3)
{
  __shared__ __align__(16) unsigned short abh[4][64][8];
  __shared__ __align__(16) unsigned short abl[4][64][8];
  const int lane = threadIdx.x;
  const int lo = lane & 15, hi = lane >> 4;
  const int row = blockIdx.x * 16 + lo;

  // layer-1 A frags: con = [node(32) | link(32) | m(32)] — node/link direct, m packed
  const int nd = l2n[row];
  const size_t no = (size_t)nd * 32 + hi * 8;
  const size_t ro = (size_t)row * 32 + hi * 8;
  s16x8 f0h = *(const s16x8*)(nsh + no);
  s16x8 f0l = *(const s16x8*)(nsl + no);
  s16x8 f1h = *(const s16x8*)(lsih + ro);
  s16x8 f1l = *(const s16x8*)(lsil + ro);
  s16x8 f2h, f2l;
  {
    const float4* a2p = (const float4*)(ms + ro);
    pack8s(a2p[0], a2p[1], f2h, f2l);
  }

#define WH(F) (*(const s16x8*)(wf + (size_t)(F) * 512 + lane * 8))
#define WL(F) (*(const s16x8*)(wf + (size_t)((F) + 64) * 512 + lane * 8))

  // layer 1 -> abuf (A-frag order for layer 2)
#pragma unroll
  for (int nt = 0; nt < 8; ++nt) {
    float bias = be1[nt * 16 + lo];
    f32x4 acc = {bias, bias, bias, bias};
    MM3(acc, f0h, f0l, WH(nt * 3 + 0), WL(nt * 3 + 0));
    MM3(acc, f1h, f1l, WH(nt * 3 + 1), WL(nt * 3 + 1));
    MM3(acc, f2h, f2l, WH(nt * 3 + 2), WL(nt * 3 + 2));
#pragma unroll
    for (int q = 0; q < 4; ++q) {
      float v = fmaxf(acc[q], 0.f);
      int rrow = hi * 4 + q, col = nt * 16 + lo;
      unsigned short h_, l_;
      splitf(v, h_, l_);
      abh[col >> 5][rrow + 16 * ((col >> 3) & 3)][col & 7] = h_;
      abl[col >> 5][rrow + 16 * ((col >> 3) & 3)][col & 7] = l_;
    }
  }
  __syncthreads();
  s16x8 x0h = *(const s16x8*)&abh[0][lane][0];
  s16x8 x1h = *(const s16x8*)&abh[1][lane][0];
  s16x8 x2h = *(const s16x8*)&abh[2][lane][0];
  s16x8 x3h = *(const s16x8*)&abh[3][lane][0];
  s16x8 x0l = *(const s16x8*)&abl[0][lane][0];
  s16x8 x1l = *(const s16x8*)&abl[1][lane][0];
  s16x8 x2l = *(const s16x8*)&abl[2][lane][0];
  s16x8 x3l = *(const s16x8*)&abl[3][lane][0];
  __syncthreads();

  // layer 2 -> abuf
#pragma unroll
  for (int nt = 0; nt < 8; ++nt) {
    float bias = be2[nt * 16 + lo];
    f32x4 acc = {bias, bias, bias, bias};
    MM3(acc, x0h, x0l, WH(24 + nt * 4 + 0), WL(24 + nt * 4 + 0));
    MM3(acc, x1h, x1l, WH(24 + nt * 4 + 1), WL(24 + nt * 4 + 1));
    MM3(acc, x2h, x2l, WH(24 + nt * 4 + 2), WL(24 + nt * 4 + 2));
    MM3(acc, x3h, x3l, WH(24 + nt * 4 + 3), WL(24 + nt * 4 + 3));
#pragma unroll
    for (int q = 0; q < 4; ++q) {
      float v = fmaxf(acc[q], 0.f);
      int rrow = hi * 4 + q, col = nt * 16 + lo;
      unsigned short h_, l_;
      splitf(v, h_, l_);
      abh[col >> 5][rrow + 16 * ((col >> 3) & 3)][col & 7] = h_;
      abl[col >> 5][rrow + 16 * ((col >> 3) & 3)][col & 7] = l_;
    }
  }
  __syncthreads();
  x0h = *(const s16x8*)&abh[0][lane][0];
  x1h = *(const s16x8*)&abh[1][lane][0];
  x2h = *(const s16x8*)&abh[2][lane][0];
  x3h = *(const s16x8*)&abh[3][lane][0];
  x0l = *(const s16x8*)&abl[0][lane][0];
  x1l = *(const s16x8*)&abl[1][lane][0];
  x2l = *(const s16x8*)&abl[2][lane][0];
  x3l = *(const s16x8*)&abl[3][lane][0];

  // layer 3 (no relu) -> split-bf16 link state out
#pragma unroll
  for (int nt = 0; nt < 2; ++nt) {
    float bias = be3[nt * 16 + lo];
    f32x4 acc = {bias, bias, bias, bias};
    MM3(acc, x0h, x0l, WH(56 + nt * 4 + 0), WL(56 + nt * 4 + 0));
    MM3(acc, x1h, x1l, WH(56 + nt * 4 + 1), WL(56 + nt * 4 + 1));
    MM3(acc, x2h, x2l, WH(56 + nt * 4 + 2), WL(56 + nt * 4 + 2));
    MM3(acc, x3h, x3l, WH(56 + nt * 4 + 3), WL(56 + nt * 4 + 3));
#pragma unroll
    for (int q = 0; q < 4; ++q) {
      unsigned short h_, l_;
      splitf(acc[q], h_, l_);
      size_t o = (size_t)(blockIdx.x * 16 + hi * 4 + q) * 32 + nt * 16 + lo;
      lsoh[o] = h_;
      lsol[o] = l_;
    }
  }
#undef WH
#undef WL
}

// ---------------- link->node segment sum (reads split link state) ----------------
__global__ void k_agg(const unsigned short* __restrict__ lsh_, const unsigned short* __restrict__ lsl_,
                      const int* __restrict__ l2n, const int* __restrict__ n2l,
                      float* __restrict__ agg)
{
  int id = blockIdx.x * 256 + threadIdx.x;
  if (id >= NLK * 32) return;
  int link = id >> 5, d = id & 31;
  size_t src = (size_t)n2l[link] * 32 + d;
  float v = bf2f(lsh_[src]) + bf2f(lsl_[src]);
  atomicAdd(agg + (size_t)l2n[link] * 32 + d, v);
}

// ---------------- con2 @ Wg -> split-bf16 cw, layout [32][4096] ----------------
__global__ void k_con2w(const unsigned short* __restrict__ nsh, const unsigned short* __restrict__ nsl,
                        const float* __restrict__ agg, const float* __restrict__ Wg,
                        unsigned short* __restrict__ cwbh, unsigned short* __restrict__ cwbl)
{
  int g = blockIdx.x * 256 + threadIdx.x;  // 32*4096
  int d = g >> 12, n = g & 4095;
  float a = 0.f;
#pragma unroll
  for (int i = 0; i < 32; ++i) {
    float nv = bf2f(nsh[n * 32 + i]) + bf2f(nsl[n * 32 + i]);
    a = fmaf(nv, Wg[i * 32 + d], a);
  }
#pragma unroll
  for (int i = 0; i < 32; ++i) a = fmaf(agg[n * 32 + i], Wg[(32 + i) * 32 + d], a);
  unsigned short h_, l_;
  splitf(a, h_, l_);
  cwbh[g] = h_;
  cwbl[g] = l_;
}

// ---------------- laplacian @ cw + bg -> split node_state, via split-bf16 MFMA ----------------
__global__ __launch_bounds__(512) void k_lap_mfma(
    const float* __restrict__ lap, const unsigned short* __restrict__ cwbh,
    const unsigned short* __restrict__ cwbl, const float* __restrict__ bg,
    unsigned short* __restrict__ nsh, unsigned short* __restrict__ nsl)
{
  __shared__ float red[8][2][64][4];
  const int lane = threadIdx.x & 63;
  const int w = threadIdx.x >> 6;
  const int lo = lane & 15, hi = lane >> 4;
  const int rowbase = blockIdx.x * 16;
  const size_t arow = (size_t)(rowbase + lo) * 4096;
  f32x4 acc0 = {0.f, 0.f, 0.f, 0.f}, acc1 = {0.f, 0.f, 0.f, 0.f};
  const int kb0 = w * 512;
#pragma unroll 4
  for (int ks = 0; ks < 16; ++ks) {
    const int kb = kb0 + ks * 32;
    const float4* ap = (const float4*)(lap + arow + kb + hi * 8);
    s16x8 ah, al;
    pack8s(ap[0], ap[1], ah, al);
    const size_t boff = (size_t)lo * 4096 + kb + hi * 8;
    s16x8 bh0 = *(const s16x8*)(cwbh + boff);
    s16x8 bl0 = *(const s16x8*)(cwbl + boff);
    s16x8 bh1 = *(const s16x8*)(cwbh + boff + 16 * 4096);
    s16x8 bl1 = *(const s16x8*)(cwbl + boff + 16 * 4096);
    MM3(acc0, ah, al, bh0, bl0);
    MM3(acc1, ah, al, bh1, bl1);
  }
  *(f32x4*)&red[w][0][lane][0] = acc0;
  *(f32x4*)&red[w][1][lane][0] = acc1;
  __syncthreads();
  if (w < 2) {
    f32x4 s = {0.f, 0.f, 0.f, 0.f};
#pragma unroll
    for (int ww = 0; ww < 8; ++ww) {
      f32x4 v = *(const f32x4*)&red[ww][w][lane][0];
      s[0] += v[0]; s[1] += v[1]; s[2] += v[2]; s[3] += v[3];
    }
    const float b = bg[w * 16 + lo];
#pragma unroll
    for (int q = 0; q < 4; ++q) {
      unsigned short h_, l_;
      splitf(s[q] + b, h_, l_);
      size_t o = (size_t)(rowbase + hi * 4 + q) * 32 + w * 16 + lo;
      nsh[o] = h_;
      nsl[o] = l_;
    }
  }
}

// ---------------- fused readout: r1 -> r2 -> out, 16 paths/block, 4 waves ----------------
__global__ __launch_bounds__(256) void k_read(
    const float* __restrict__ psb, const unsigned short* __restrict__ rw,
    const float* __restrict__ br1, const float* __restrict__ br2,
    const float* __restrict__ Wf, const float* __restrict__ bf,
    float* __restrict__ out)
{
  __shared__ __align__(16) unsigned short r1h[8][64][8];
  __shared__ __align__(16) unsigned short r1l[8][64][8];
  __shared__ float red[4][4][4];
  const int lane = threadIdx.x & 63;
  const int w = threadIdx.x >> 6;
  const int lo = lane & 15, hi = lane >> 4;
  const int pb = blockIdx.x * 16;

#define RH1(NT) (*(const s16x8*)(rw + (size_t)(NT) * 512 + lane * 8))
#define RL1(NT) (*(const s16x8*)(rw + (size_t)((NT) + 16) * 512 + lane * 8))
#define RH2(NT, KS) (*(const s16x8*)(rw + (size_t)(32 + (NT) * 8 + (KS)) * 512 + lane * 8))
#define RL2(NT, KS) (*(const s16x8*)(rw + (size_t)(160 + (NT) * 8 + (KS)) * 512 + lane * 8))

  // A-frag from psb: row = lo, k = hi*8+e
  s16x8 pAh, pAl;
  {
    const float4* pp = (const float4*)(psb + (size_t)(pb + lo) * 32 + hi * 8);
    pack8s(pp[0], pp[1], pAh, pAl);
  }

  // layer 1: r1 = relu(psb @ Wr1 + br1), staged to LDS in A-frag order
#pragma unroll
  for (int j = 0; j < 4; ++j) {
    const int nt = w * 4 + j;
    float bias = br1[nt * 16 + lo];
    f32x4 acc = {bias, bias, bias, bias};
    MM3(acc, pAh, pAl, RH1(nt), RL1(nt));
#pragma unroll
    for (int q = 0; q < 4; ++q) {
      float v = fmaxf(acc[q], 0.f);
      int rrow = hi * 4 + q, col = nt * 16 + lo;
      unsigned short h_, l_;
      splitf(v, h_, l_);
      r1h[col >> 5][rrow + 16 * ((col >> 3) & 3)][col & 7] = h_;
      r1l[col >> 5][rrow + 16 * ((col >> 3) & 3)][col & 7] = l_;
    }
  }
  __syncthreads();

  s16x8 xh[8], xl[8];
#pragma unroll
  for (int ks = 0; ks < 8; ++ks) {
    xh[ks] = *(const s16x8*)&r1h[ks][lane][0];
    xl[ks] = *(const s16x8*)&r1l[ks][lane][0];
  }

  // layer 2 + in-register Wf dot: partial[q] = sum over this wave's cols
  float partial[4] = {0.f, 0.f, 0.f, 0.f};
#pragma unroll
  for (int j = 0; j < 4; ++j) {
    const int nt = w * 4 + j;
    float bias = br2[nt * 16 + lo];
    f32x4 acc = {bias, bias, bias, bias};
#pragma unroll
    for (int ks = 0; ks < 8; ++ks)
      MM3(acc, xh[ks], xl[ks], RH2(nt, ks), RL2(nt, ks));
    const float wfv = Wf[nt * 16 + lo];
#pragma unroll
    for (int q = 0; q < 4; ++q)
      partial[q] = fmaf(fmaxf(acc[q], 0.f), wfv, partial[q]);
  }
  // reduce across the 16 lo lanes (lane bits 0..3)
#pragma unroll
  for (int m = 1; m <= 8; m <<= 1) {
#pragma unroll
    for (int q = 0; q < 4; ++q) partial[q] += __shfl_xor(partial[q], m);
  }
  if (lo == 0) {
#pragma unroll
    for (int q = 0; q < 4; ++q) red[w][hi][q] = partial[q];
  }
  __syncthreads();
  if (threadIdx.x < 16) {
    const int row = threadIdx.x, h2 = row >> 2, q2 = row & 3;
    float s = red[0][h2][q2] + red[1][h2][q2] + red[2][h2][q2] + red[3][h2][q2] + bf[0];
    const float4* pr = (const float4*)(psb + (size_t)(pb + row) * 32);
    const float4* wt = (const float4*)(Wf + 256);
#pragma unroll
    for (int i = 0; i < 8; ++i) {
      float4 v = pr[i], t = wt[i];
      s += v.x * t.x + v.y * t.y + v.z * t.z + v.w * t.w;
    }
    out[pb + row] = s;
  }
#undef RH1
#undef RL1
#undef RH2
#undef RL2
}

extern "C" void kernel_launch(void* const* d_in, const int* in_sizes, int n_in,
                              void* d_out, int out_size, void* d_ws, size_t ws_size,
                              hipStream_t stream) {
  const float* capacities = (const float*)d_in[0];
  const float* degrees    = (const float*)d_in[1];
  const float* traffic    = (const float*)d_in[2];
  const float* lap        = (const float*)d_in[3];
  const int*   l2p        = (const int*)d_in[6];
  const int*   n2p        = (const int*)d_in[7];
  const int*   l2n        = (const int*)d_in[8];
  const int*   n2l        = (const int*)d_in[9];
  const float* gk  = (const float*)d_in[13];
  const float* grk = (const float*)d_in[14];
  const float* gb  = (const float*)d_in[15];
  const float* We1 = (const float*)d_in[16]; const float* be1 = (const float*)d_in[17];
  const float* We2 = (const float*)d_in[18]; const float* be2 = (const float*)d_in[19];
  const float* We3 = (const float*)d_in[20]; const float* be3 = (const float*)d_in[21];
  const float* Wg  = (const float*)d_in[22]; const float* bg  = (const float*)d_in[23];
  const float* Wr1 = (const float*)d_in[24]; const float* br1 = (const float*)d_in[25];
  const float* Wr2 = (const float*)d_in[26]; const float* br2 = (const float*)d_in[27];
  const float* Wf  = (const float*)d_in[28]; const float* bf  = (const float*)d_in[29];

  float* w = (float*)d_ws;
  unsigned short* lsh0 = (unsigned short*)(w + OFF_LSH0);
  unsigned short* lsl0 = (unsigned short*)(w + OFF_LSL0);
  unsigned short* lsh1 = (unsigned short*)(w + OFF_LSH1);
  unsigned short* lsl1 = (unsigned short*)(w + OFF_LSL1);
  float* ms  = w + OFF_MS;
  float* agg = w + OFF_AGG;
  unsigned short* nsh = (unsigned short*)(w + OFF_NSH);
  unsigned short* nsl = (unsigned short*)(w + OFF_NSL);
  unsigned short* cwbh = (unsigned short*)(w + OFF_CWB);
  unsigned short* cwbl = cwbh + 32 * 4096;
  unsigned short* wfb = (unsigned short*)(w + OFF_WF);
  unsigned short* rwb = (unsigned short*)(w + OFF_RW);
  float* psb = w + OFF_PS;

  k_init<<<6250, 256, 0, stream>>>(capacities, degrees, traffic, lsh0, lsl0, nsh, nsl, psb);
  k_prep<<<16, 256, 0, stream>>>(We1, We2, We3, wfb);
  k_prep2<<<36, 256, 0, stream>>>(Wr1, Wr2, rwb);
  for (int t = 0; t < 4; ++t) {
    unsigned short* lih = (t & 1) ? lsh1 : lsh0;
    unsigned short* lil = (t & 1) ? lsl1 : lsl0;
    unsigned short* loh = (t & 1) ? lsh0 : lsh1;
    unsigned short* lol = (t & 1) ? lsl0 : lsl1;
    hipMemsetAsync(ms, 0, (size_t)NLK * 32 * sizeof(float), stream);
    hipMemsetAsync(agg, 0, (size_t)NNODE * 32 * sizeof(float), stream);
    k_gru_mfma<<<1250, 128, 0, stream>>>(lih, lil, nsh, nsl, psb, l2p, n2p, gk, grk, gb, ms);
    k_mlp_mfma<<<3125, 64, 0, stream>>>(lih, lil, loh, lol, nsh, nsl, ms, l2n, wfb, be1, be2, be3);
    k_agg<<<6250, 256, 0, stream>>>(loh, lol, l2n, n2l, agg);
    k_con2w<<<512, 256, 0, stream>>>(nsh, nsl, agg, Wg, cwbh, cwbl);
    k_lap_mfma<<<256, 512, 0, stream>>>(lap, cwbh, cwbl, bg, nsh, nsl);
  }
  k_read<<<1250, 256, 0, stream>>>(psb, rwb, br1, br2, Wf, bf, (float*)d_out);
}